// Round 1
// baseline (461.353 us; speedup 1.0000x reference)
//
#include <hip/hip_runtime.h>
#include <hip/hip_bf16.h>

#define B_ 4
#define S_ 1024
#define E_ 1280
#define H_ 16
#define D_ 80
#define M_ (B_*S_)   // 4096

typedef __hip_bfloat16 bf16;
using bf16x8 = __attribute__((ext_vector_type(8))) short;  // 8 bf16 = 4 VGPRs
using f32x4  = __attribute__((ext_vector_type(4))) float;  // MFMA C/D frag

__device__ __forceinline__ float b2f(bf16 x){ return __bfloat162float(x); }
__device__ __forceinline__ bf16  f2b(float x){ return __float2bfloat16(x); }
__device__ __forceinline__ void  stf(float* p, float v){ *p = v; }
__device__ __forceinline__ void  stf(bf16*  p, float v){ *p = f2b(v); }

__device__ __forceinline__ void gload_lds16(const void* g, void* l) {
    __builtin_amdgcn_global_load_lds(
        (const __attribute__((address_space(1))) unsigned int*)g,
        (__attribute__((address_space(3))) unsigned int*)l, 16, 0, 0);
}

// fp32 -> bf16 conversion, 8 elems/thread. blockIdx.y selects segment.
__global__ __launch_bounds__(256) void cvt_kernel(
    const float* __restrict__ s0, const float* __restrict__ s1,
    const float* __restrict__ s2, const float* __restrict__ s3,
    const float* __restrict__ s4,
    bf16* __restrict__ d0, bf16* __restrict__ d1, bf16* __restrict__ d2,
    bf16* __restrict__ d3, bf16* __restrict__ d4,
    int n0, int n1)
{
    const float* s; bf16* d; int n;
    switch (blockIdx.y) {
        case 0: s = s0; d = d0; n = n0; break;
        case 1: s = s1; d = d1; n = n1; break;
        case 2: s = s2; d = d2; n = n1; break;
        case 3: s = s3; d = d3; n = n1; break;
        default: s = s4; d = d4; n = n1; break;
    }
    int i = (blockIdx.x * 256 + threadIdx.x) * 8;
    if (i >= n) return;
    float4 a = *(const float4*)(s + i);
    float4 b = *(const float4*)(s + i + 4);
    bf16 t[8];
    t[0]=f2b(a.x); t[1]=f2b(a.y); t[2]=f2b(a.z); t[3]=f2b(a.w);
    t[4]=f2b(b.x); t[5]=f2b(b.y); t[6]=f2b(b.z); t[7]=f2b(b.w);
    *(uint4*)(d + i) = *(const uint4*)t;
}

// m97-style MFMA GEMM, BK=64 (two [128][32] LDS panels per operand).
// C[m,n] = sum_k A[m,k]*W[n,k] + bias[n]
// VT_OUT: mat==2 (V) stores transposed as VT[btok][h][d][key].
template<typename TC, bool VT_OUT>
__global__ __launch_bounds__(256) void mfma_gemm_bt(
    const bf16* __restrict__ A,
    const bf16* __restrict__ W0, const bf16* __restrict__ W1, const bf16* __restrict__ W2,
    const float* __restrict__ b0, const float* __restrict__ b1, const float* __restrict__ b2,
    TC* __restrict__ C0, TC* __restrict__ C1, TC* __restrict__ C2,
    int K, int N, int ntiles)
{
    const int mat = blockIdx.y / ntiles;
    const int bn  = (blockIdx.y % ntiles) * 128;
    const int bm  = blockIdx.x * 128;
    const bf16* W; const float* bias; TC* C;
    if (mat == 0)      { W = W0; bias = b0; C = C0; }
    else if (mat == 1) { W = W1; bias = b1; C = C1; }
    else               { W = W2; bias = b2; C = C2; }

    __shared__ bf16 As[2][128][32];   // panel p covers k0 + p*32 .. +32
    __shared__ bf16 Ws[2][128][32];

    const int tid  = threadIdx.x;
    const int lane = tid & 63;
    const int wv   = tid >> 6;
    const int wm   = (wv & 1) * 64;
    const int wn   = (wv >> 1) * 64;
    const int srow = wv * 16 + (lane >> 2);
    const int scol = (lane & 3) * 8;

    f32x4 acc[4][4] = {};

    for (int k0 = 0; k0 < K; k0 += 64) {
        __syncthreads();
        #pragma unroll
        for (int p = 0; p < 2; p++) {
            const int kc = k0 + p*32 + scol;
            gload_lds16(A + (size_t)(bm + srow)      * K + kc, &As[p][wv*16][0]);
            gload_lds16(A + (size_t)(bm + 64 + srow) * K + kc, &As[p][64 + wv*16][0]);
            gload_lds16(W + (size_t)(bn + srow)      * K + kc, &Ws[p][wv*16][0]);
            gload_lds16(W + (size_t)(bn + 64 + srow) * K + kc, &Ws[p][64 + wv*16][0]);
        }
        __syncthreads();

        const int fr = lane & 15;
        const int kq = (lane >> 4) * 8;
        #pragma unroll
        for (int p = 0; p < 2; p++) {
            bf16x8 af[4], wf[4];
            #pragma unroll
            for (int t = 0; t < 4; t++) {
                af[t] = *(const bf16x8*)&As[p][wm + t*16 + fr][kq];
                wf[t] = *(const bf16x8*)&Ws[p][wn + t*16 + fr][kq];
            }
            #pragma unroll
            for (int mt = 0; mt < 4; mt++)
                #pragma unroll
                for (int nt = 0; nt < 4; nt++)
                    acc[mt][nt] = __builtin_amdgcn_mfma_f32_16x16x32_bf16(
                        af[mt], wf[nt], acc[mt][nt], 0, 0, 0);
        }
    }

    const int col_l = lane & 15;
    const int row_l = (lane >> 4) * 4;

    if (VT_OUT && mat == 2) {
        const int btok = bm >> 10;
        const int keyb = (bm & 1023) + wm + row_l;
        #pragma unroll
        for (int nt = 0; nt < 4; nt++) {
            const int n = bn + wn + nt*16 + col_l;
            const float bv = bias[n];
            const int hh = n / 80, dd = n % 80;
            bf16* vbase = (bf16*)C + ((size_t)(btok*H_ + hh)*D_ + dd)*S_ + keyb;
            #pragma unroll
            for (int mt = 0; mt < 4; mt++) {
                union { bf16 h[4]; uint2 u; } t4;
                #pragma unroll
                for (int r = 0; r < 4; r++) t4.h[r] = f2b(acc[mt][nt][r] + bv);
                *(uint2*)&vbase[mt*16] = t4.u;
            }
        }
    } else {
        #pragma unroll
        for (int nt = 0; nt < 4; nt++) {
            const int n = bn + wn + nt*16 + col_l;
            const float bv = bias[n];
            #pragma unroll
            for (int mt = 0; mt < 4; mt++) {
                #pragma unroll
                for (int r = 0; r < 4; r++) {
                    const int m = bm + wm + mt*16 + row_l + r;
                    stf(&C[(size_t)m * N + n], acc[mt][nt][r] + bv);
                }
            }
        }
    }
}

// rope helper: lo=dims j..j+8 (j<40), hi=j+40.. ; out_lo = x1*c - x2*s, out_hi = x2*c + x1*s
__device__ __forceinline__ void rope8(const bf16* lo, const bf16* hi,
                                      const float* cp, const float* sp,
                                      float mul, uint4* out_lo, uint4* out_hi)
{
    union { uint4 u; bf16 h[8]; } li, hi_, lo_o, hi_o;
    li.u  = *(const uint4*)lo;
    hi_.u = *(const uint4*)hi;
    #pragma unroll
    for (int u = 0; u < 8; u++) {
        float x1 = b2f(li.h[u]), x2 = b2f(hi_.h[u]);
        float c = cp[u], s = sp[u];
        lo_o.h[u] = f2b((x1*c - x2*s) * mul);
        hi_o.h[u] = f2b((x2*c + x1*s) * mul);
    }
    *out_lo = lo_o.u;
    *out_hi = hi_o.u;
}

// One-shot in-place RoPE over q and k. Q additionally pre-scaled by 1/sqrt(80).
// Thread t handles one 8-wide lo/hi pair-chunk: 4096 rows x 16 heads x 5 chunks
// per tensor = 327680 threads/tensor; grid covers q then k.
__global__ __launch_bounds__(256) void rope_kernel(
    bf16* __restrict__ qp, bf16* __restrict__ kp,
    const float* __restrict__ cosp, const float* __restrict__ sinp)
{
    int idx = blockIdx.x * 256 + threadIdx.x;
    const int NT = M_ * H_ * 5;   // 327680
    bf16* base; float mul;
    if (idx < NT) { base = qp; mul = 0.11180339887498949f; }
    else         { base = kp; mul = 1.0f; idx -= NT; }
    const int row = idx / 80;          // token 0..4095
    const int rem = idx - row * 80;
    const int h   = rem / 5;
    const int pc  = rem - h * 5;
    const int s   = row & (S_ - 1);
    bf16* p = base + (size_t)row * E_ + h * D_ + pc * 8;
    const float* cp = cosp + s * D_ + pc * 8;
    const float* sp = sinp + s * D_ + pc * 8;
    uint4 olo, ohi;
    rope8(p, p + 40, cp, sp, mul, &olo, &ohi);
    *(uint4*)p        = olo;
    *(uint4*)(p + 40) = ohi;
}

// MFMA flash attention v8 — barrier-free, staging-free.
// Q/K pre-roped (rope_kernel); Q pre-scaled. K and V fragments are loaded
// per-wave directly from global (K/V tiles are 10 KB each: L1-resident; the
// XCD swizzle below pins all 16 q-tiles of one (b,h) to the same XCD so its
// 320 KB of K/V stays in that XCD's L2). Only LDS use is the per-wave 2.25 KB
// P^T transpose buffer -> 9.2 KB/block, 8 blocks/CU, zero __syncthreads.
// Varlen tile skipping as before (lens are multiples of 64 here):
//  - valid q-tile: iterate len/64 k-tiles, no masking.
//  - invalid q-tile (reference: uniform softmax over all 1024 keys): PT=1,
//    PV-only over 16 tiles, normalize 1/1024.
//  - len%64 != 0 (not this instance): full 16-tile masked fallback.
__global__ __launch_bounds__(256, 8) void attn_mfma(
    const bf16* __restrict__ q, const bf16* __restrict__ k, const bf16* __restrict__ vt,
    const int* __restrict__ cu, bf16* __restrict__ o)
{
    __shared__ __align__(16) bf16 PTs[4][16 * 72];   // per-wave P^T [16][72]

    // XCD-aware swizzle: xcd = n&7 constant for all 16 q-tiles of a (b,h).
    const int n  = blockIdx.x;
    const int g  = (n & 7) * 8 + (n >> 7);   // (b,h) group 0..63
    const int qt = (n >> 3) & 15;            // q-tile 0..15
    const int b  = g >> 4;
    const int h  = g & 15;

    const int tid  = threadIdx.x;
    const int lane = tid & 63, wv = tid >> 6;
    const int quad = lane >> 4, l15 = lane & 15;
    const int q0   = qt * 64;
    const int len  = cu[b + 1] - cu[b];

    const bool uniformq = (q0 >= len);
    const bool cleanlen = ((len & 63) == 0);
    const int  ktiles   = uniformq ? 16 : (cleanlen ? (len >> 6) : 16);
    const bool domask   = !uniformq && !cleanlen;

    bf16* PT = &PTs[wv][0];

    // Q fragments straight to registers (pre-roped, pre-scaled).
    // k-step 2 covers dims 64..95: quad>=2 (dims 80..95) is zero-padded.
    bf16x8 qf[3] = {};
    if (!uniformq) {
        const bf16* qrow = q + (size_t)(b*S_ + q0 + wv*16 + l15)*E_ + h*D_ + quad*8;
        qf[0] = *(const bf16x8*)(qrow);
        qf[1] = *(const bf16x8*)(qrow + 32);
        if (quad < 2) qf[2] = *(const bf16x8*)(qrow + 64);
    } else {
        // uniform path: PT = 1 for all 16 rows x 64 cols (written once)
        const bf16 one = f2b(1.0f);
        #pragma unroll
        for (int nt = 0; nt < 4; nt++)
            #pragma unroll
            for (int r = 0; r < 4; r++)
                PT[(quad*4 + r)*72 + nt*16 + l15] = one;
    }

    float m_r[4], l_r[4];
    #pragma unroll
    for (int r = 0; r < 4; r++) { m_r[r] = -1e30f; l_r[r] = 0.f; }
    f32x4 o_acc[5] = {};

    const bool q_full = (q0 + 64) <= len;

    const bf16* kbase0 = k  + (size_t)(b*S_ + l15)*E_ + h*D_ + quad*8;
    const bf16* vbase0 = vt + ((size_t)(b*H_ + h)*D_ + l15)*S_ + quad*8;

    for (int kt = 0; kt < ktiles; kt++) {
        if (!uniformq) {
            // ---- QK^T: 4 n-tiles x (2 full + 1 zero-padded) ksteps,
            //      K frags direct from global (L1/L2-resident)
            f32x4 s4[4];
            const bf16* kb = kbase0 + (size_t)kt * 64 * E_;
            #pragma unroll
            for (int nt = 0; nt < 4; nt++) {
                const bf16* krow = kb + (size_t)nt * 16 * E_;
                bf16x8 kf0 = *(const bf16x8*)(krow);
                bf16x8 kf1 = *(const bf16x8*)(krow + 32);
                bf16x8 kf2 = {};
                if (quad < 2) kf2 = *(const bf16x8*)(krow + 64);
                f32x4 a0 = {};
                a0 = __builtin_amdgcn_mfma_f32_16x16x32_bf16(qf[0], kf0, a0, 0, 0, 0);
                a0 = __builtin_amdgcn_mfma_f32_16x16x32_bf16(qf[1], kf1, a0, 0, 0, 0);
                a0 = __builtin_amdgcn_mfma_f32_16x16x32_bf16(qf[2], kf2, a0, 0, 0, 0);
                s4[nt] = a0;
            }

            // ---- online softmax (rows quad*4+r, wave-exclusive)
            float sv[4][4];
            if (!domask || (q_full && (kt*64 + 64) <= len)) {
                #pragma unroll
                for (int r = 0; r < 4; r++)
                    #pragma unroll
                    for (int nt = 0; nt < 4; nt++)
                        sv[nt][r] = s4[nt][r];
            } else {
                bool vk[4];
                #pragma unroll
                for (int nt = 0; nt < 4; nt++) vk[nt] = (kt*64 + nt*16 + l15) < len;
                #pragma unroll
                for (int r = 0; r < 4; r++) {
                    const bool vq = (q0 + wv*16 + quad*4 + r) < len;
                    #pragma unroll
                    for (int nt = 0; nt < 4; nt++)
                        sv[nt][r] = (vq && vk[nt]) ? s4[nt][r] : -1e9f;
                }
            }
            float rmax[4];
            #pragma unroll
            for (int r = 0; r < 4; r++)
                rmax[r] = fmaxf(fmaxf(sv[0][r], sv[1][r]), fmaxf(sv[2][r], sv[3][r]));
            #pragma unroll
            for (int st = 1; st < 16; st <<= 1)
                #pragma unroll
                for (int r = 0; r < 4; r++)
                    rmax[r] = fmaxf(rmax[r], __shfl_xor(rmax[r], st, 64));
            float mnew[4], alpha[4], rsum[4], p[4][4];
            #pragma unroll
            for (int r = 0; r < 4; r++) {
                mnew[r]  = fmaxf(m_r[r], rmax[r]);
                alpha[r] = __expf(m_r[r] - mnew[r]);
                float a = 0.f;
                #pragma unroll
                for (int nt = 0; nt < 4; nt++) { p[nt][r] = __expf(sv[nt][r] - mnew[r]); a += p[nt][r]; }
                rsum[r] = a;
            }
            #pragma unroll
            for (int st = 1; st < 16; st <<= 1)
                #pragma unroll
                for (int r = 0; r < 4; r++)
                    rsum[r] += __shfl_xor(rsum[r], st, 64);
            #pragma unroll
            for (int r = 0; r < 4; r++) {
                l_r[r] = l_r[r] * alpha[r] + rsum[r];
                m_r[r] = mnew[r];
            }
            #pragma unroll
            for (int dt = 0; dt < 5; dt++)
                #pragma unroll
                for (int r = 0; r < 4; r++)
                    o_acc[dt][r] *= alpha[r];
            // P (C-layout) -> PT (A-layout); same-wave LDS RAW, no barrier needed
            #pragma unroll
            for (int nt = 0; nt < 4; nt++)
                #pragma unroll
                for (int r = 0; r < 4; r++)
                    PT[(quad*4 + r)*72 + nt*16 + l15] = f2b(p[nt][r]);
        }

        // ---- PV: V B-frags direct from global VT[b][h][d][key]
        bf16x8 pa[2];
        pa[0] = *(const bf16x8*)&PT[l15*72 + quad*8];
        pa[1] = *(const bf16x8*)&PT[l15*72 + 32 + quad*8];
        const bf16* vb = vbase0 + kt * 64;
        #pragma unroll
        for (int dt = 0; dt < 5; dt++) {
            #pragma unroll
            for (int ks = 0; ks < 2; ks++) {
                bf16x8 vf = *(const bf16x8*)(vb + (size_t)dt*16*S_ + ks*32);
                o_acc[dt] = __builtin_amdgcn_mfma_f32_16x16x32_bf16(pa[ks], vf, o_acc[dt], 0, 0, 0);
            }
        }
    }

    // ---- epilogue
    #pragma unroll
    for (int r = 0; r < 4; r++) {
        const float inv = uniformq ? (1.0f / 1024.0f) : (1.0f / l_r[r]);
        size_t row_g = (size_t)(b*S_ + q0 + wv*16 + quad*4 + r);
        #pragma unroll
        for (int dt = 0; dt < 5; dt++)
            o[row_g*E_ + h*D_ + dt*16 + l15] = f2b(o_acc[dt][r] * inv);
    }
}

extern "C" void kernel_launch(void* const* d_in, const int* in_sizes, int n_in,
                              void* d_out, int out_size, void* d_ws, size_t ws_size,
                              hipStream_t stream)
{
    const float* x    = (const float*)d_in[0];
    const int*   cu   = (const int*)  d_in[1];
    const float* cosp = (const float*)d_in[2];
    const float* sinp = (const float*)d_in[3];
    const float* wq   = (const float*)d_in[4];
    const float* bq   = (const float*)d_in[5];
    const float* wk   = (const float*)d_in[6];
    const float* bk   = (const float*)d_in[7];
    const float* wv   = (const float*)d_in[8];
    const float* bv   = (const float*)d_in[9];
    const float* wo   = (const float*)d_in[10];
    const float* bo   = (const float*)d_in[11];
    float* out = (float*)d_out;

    bf16* q   = (bf16*)d_ws;
    bf16* kk  = q   + (size_t)M_ * E_;
    bf16* vt  = kk  + (size_t)M_ * E_;   // transposed V: [B][H][D][S]
    bf16* ao  = vt  + (size_t)M_ * E_;
    bf16* xb  = ao  + (size_t)M_ * E_;
    bf16* wqb = xb  + (size_t)M_ * E_;
    bf16* wkb = wqb + (size_t)E_ * E_;
    bf16* wvb = wkb + (size_t)E_ * E_;
    bf16* wob = wvb + (size_t)E_ * E_;

    // 0) convert x + 4 weight matrices to bf16
    cvt_kernel<<<dim3(2560, 5), 256, 0, stream>>>(
        x, wq, wk, wv, wo, xb, wqb, wkb, wvb, wob, M_*E_, E_*E_);

    // 1) QKV projection (MFMA, BK=64), bias fused; V written transposed.
    mfma_gemm_bt<bf16, true><<<dim3(M_/128, 30), 256, 0, stream>>>(
        xb, wqb, wkb, wvb, bq, bk, bv, q, kk, vt, E_, E_, 10);

    // 1.5) one-shot RoPE on q (pre-scaled) and k, in place
    rope_kernel<<<2560, 256, 0, stream>>>(q, kk, cosp, sinp);

    // 2) MFMA flash attention (barrier-free, staging-free, XCD swizzle)
    attn_mfma<<<1024, 256, 0, stream>>>(q, kk, vt, cu, ao);

    // 3) output projection (MFMA, BK=64), fp32 out, bias fused
    mfma_gemm_bt<float, false><<<dim3(M_/128, 10), 256, 0, stream>>>(
        ao, wob, wob, wob, bo, bo, bo, out, out, out, E_, E_, 10);
}

// Round 2
// 280.639 us; speedup vs baseline: 1.6439x; 1.6439x over previous
//
#include <hip/hip_runtime.h>
#include <hip/hip_bf16.h>

#define B_ 4
#define S_ 1024
#define E_ 1280
#define H_ 16
#define D_ 80
#define M_ (B_*S_)   // 4096

typedef __hip_bfloat16 bf16;
using bf16x8 = __attribute__((ext_vector_type(8))) short;  // 8 bf16 = 4 VGPRs
using f32x4  = __attribute__((ext_vector_type(4))) float;  // MFMA C/D frag

__device__ __forceinline__ float b2f(bf16 x){ return __bfloat162float(x); }
__device__ __forceinline__ bf16  f2b(float x){ return __float2bfloat16(x); }
__device__ __forceinline__ void  stf(float* p, float v){ *p = v; }
__device__ __forceinline__ void  stf(bf16*  p, float v){ *p = f2b(v); }

__device__ __forceinline__ void gload_lds16(const void* g, void* l) {
    __builtin_amdgcn_global_load_lds(
        (const __attribute__((address_space(1))) unsigned int*)g,
        (__attribute__((address_space(3))) unsigned int*)l, 16, 0, 0);
}

// fp32 -> bf16 conversion, 8 elems/thread. blockIdx.y selects segment.
__global__ __launch_bounds__(256) void cvt_kernel(
    const float* __restrict__ s0, const float* __restrict__ s1,
    const float* __restrict__ s2, const float* __restrict__ s3,
    const float* __restrict__ s4,
    bf16* __restrict__ d0, bf16* __restrict__ d1, bf16* __restrict__ d2,
    bf16* __restrict__ d3, bf16* __restrict__ d4,
    int n0, int n1)
{
    const float* s; bf16* d; int n;
    switch (blockIdx.y) {
        case 0: s = s0; d = d0; n = n0; break;
        case 1: s = s1; d = d1; n = n1; break;
        case 2: s = s2; d = d2; n = n1; break;
        case 3: s = s3; d = d3; n = n1; break;
        default: s = s4; d = d4; n = n1; break;
    }
    int i = (blockIdx.x * 256 + threadIdx.x) * 8;
    if (i >= n) return;
    float4 a = *(const float4*)(s + i);
    float4 b = *(const float4*)(s + i + 4);
    bf16 t[8];
    t[0]=f2b(a.x); t[1]=f2b(a.y); t[2]=f2b(a.z); t[3]=f2b(a.w);
    t[4]=f2b(b.x); t[5]=f2b(b.y); t[6]=f2b(b.z); t[7]=f2b(b.w);
    *(uint4*)(d + i) = *(const uint4*)t;
}

// m97-style MFMA GEMM, BK=64 (two [128][32] LDS panels per operand).
// C[m,n] = sum_k A[m,k]*W[n,k] + bias[n]
// VT_OUT: mat==2 (V) stores transposed as VT[btok][h][d][key].
template<typename TC, bool VT_OUT>
__global__ __launch_bounds__(256) void mfma_gemm_bt(
    const bf16* __restrict__ A,
    const bf16* __restrict__ W0, const bf16* __restrict__ W1, const bf16* __restrict__ W2,
    const float* __restrict__ b0, const float* __restrict__ b1, const float* __restrict__ b2,
    TC* __restrict__ C0, TC* __restrict__ C1, TC* __restrict__ C2,
    int K, int N, int ntiles)
{
    const int mat = blockIdx.y / ntiles;
    const int bn  = (blockIdx.y % ntiles) * 128;
    const int bm  = blockIdx.x * 128;
    const bf16* W; const float* bias; TC* C;
    if (mat == 0)      { W = W0; bias = b0; C = C0; }
    else if (mat == 1) { W = W1; bias = b1; C = C1; }
    else               { W = W2; bias = b2; C = C2; }

    __shared__ bf16 As[2][128][32];   // panel p covers k0 + p*32 .. +32
    __shared__ bf16 Ws[2][128][32];

    const int tid  = threadIdx.x;
    const int lane = tid & 63;
    const int wv   = tid >> 6;
    const int wm   = (wv & 1) * 64;
    const int wn   = (wv >> 1) * 64;
    const int srow = wv * 16 + (lane >> 2);
    const int scol = (lane & 3) * 8;

    f32x4 acc[4][4] = {};

    for (int k0 = 0; k0 < K; k0 += 64) {
        __syncthreads();
        #pragma unroll
        for (int p = 0; p < 2; p++) {
            const int kc = k0 + p*32 + scol;
            gload_lds16(A + (size_t)(bm + srow)      * K + kc, &As[p][wv*16][0]);
            gload_lds16(A + (size_t)(bm + 64 + srow) * K + kc, &As[p][64 + wv*16][0]);
            gload_lds16(W + (size_t)(bn + srow)      * K + kc, &Ws[p][wv*16][0]);
            gload_lds16(W + (size_t)(bn + 64 + srow) * K + kc, &Ws[p][64 + wv*16][0]);
        }
        __syncthreads();

        const int fr = lane & 15;
        const int kq = (lane >> 4) * 8;
        #pragma unroll
        for (int p = 0; p < 2; p++) {
            bf16x8 af[4], wf[4];
            #pragma unroll
            for (int t = 0; t < 4; t++) {
                af[t] = *(const bf16x8*)&As[p][wm + t*16 + fr][kq];
                wf[t] = *(const bf16x8*)&Ws[p][wn + t*16 + fr][kq];
            }
            #pragma unroll
            for (int mt = 0; mt < 4; mt++)
                #pragma unroll
                for (int nt = 0; nt < 4; nt++)
                    acc[mt][nt] = __builtin_amdgcn_mfma_f32_16x16x32_bf16(
                        af[mt], wf[nt], acc[mt][nt], 0, 0, 0);
        }
    }

    const int col_l = lane & 15;
    const int row_l = (lane >> 4) * 4;

    if (VT_OUT && mat == 2) {
        const int btok = bm >> 10;
        const int keyb = (bm & 1023) + wm + row_l;
        #pragma unroll
        for (int nt = 0; nt < 4; nt++) {
            const int n = bn + wn + nt*16 + col_l;
            const float bv = bias[n];
            const int hh = n / 80, dd = n % 80;
            bf16* vbase = (bf16*)C + ((size_t)(btok*H_ + hh)*D_ + dd)*S_ + keyb;
            #pragma unroll
            for (int mt = 0; mt < 4; mt++) {
                union { bf16 h[4]; uint2 u; } t4;
                #pragma unroll
                for (int r = 0; r < 4; r++) t4.h[r] = f2b(acc[mt][nt][r] + bv);
                *(uint2*)&vbase[mt*16] = t4.u;
            }
        }
    } else {
        #pragma unroll
        for (int nt = 0; nt < 4; nt++) {
            const int n = bn + wn + nt*16 + col_l;
            const float bv = bias[n];
            #pragma unroll
            for (int mt = 0; mt < 4; mt++) {
                #pragma unroll
                for (int r = 0; r < 4; r++) {
                    const int m = bm + wm + mt*16 + row_l + r;
                    stf(&C[(size_t)m * N + n], acc[mt][nt][r] + bv);
                }
            }
        }
    }
}

// rope helper: lo=dims j..j+8 (j<40), hi=j+40.. ; out_lo = x1*c - x2*s, out_hi = x2*c + x1*s
__device__ __forceinline__ void rope8(const bf16* lo, const bf16* hi,
                                      const float* cp, const float* sp,
                                      float mul, uint4* out_lo, uint4* out_hi)
{
    union { uint4 u; bf16 h[8]; } li, hi_, lo_o, hi_o;
    li.u  = *(const uint4*)lo;
    hi_.u = *(const uint4*)hi;
    #pragma unroll
    for (int u = 0; u < 8; u++) {
        float x1 = b2f(li.h[u]), x2 = b2f(hi_.h[u]);
        float c = cp[u], s = sp[u];
        lo_o.h[u] = f2b((x1*c - x2*s) * mul);
        hi_o.h[u] = f2b((x2*c + x1*s) * mul);
    }
    *out_lo = lo_o.u;
    *out_hi = hi_o.u;
}

// One-shot in-place RoPE over q and k. Q additionally pre-scaled by 1/sqrt(80).
__global__ __launch_bounds__(256) void rope_kernel(
    bf16* __restrict__ qp, bf16* __restrict__ kp,
    const float* __restrict__ cosp, const float* __restrict__ sinp)
{
    int idx = blockIdx.x * 256 + threadIdx.x;
    const int NT = M_ * H_ * 5;   // 327680
    bf16* base; float mul;
    if (idx < NT) { base = qp; mul = 0.11180339887498949f; }
    else         { base = kp; mul = 1.0f; idx -= NT; }
    const int row = idx / 80;          // token 0..4095
    const int rem = idx - row * 80;
    const int h   = rem / 5;
    const int pc  = rem - h * 5;
    const int s   = row & (S_ - 1);
    bf16* p = base + (size_t)row * E_ + h * D_ + pc * 8;
    const float* cp = cosp + s * D_ + pc * 8;
    const float* sp = sinp + s * D_ + pc * 8;
    uint4 olo, ohi;
    rope8(p, p + 40, cp, sp, mul, &olo, &ohi);
    *(uint4*)p        = olo;
    *(uint4*)(p + 40) = ohi;
}

// MFMA flash attention v9:
//  - Q/K pre-roped by rope_kernel (Q pre-scaled): no per-tile rope recompute.
//  - K and V tiles staged via global_load_lds (no staging VALU, no staging
//    bank conflicts), with XOR-swizzled layouts (swizzle applied to the
//    per-lane GLOBAL source; same involution applied on the ds_read side):
//      K: [64][80], slot(16B units, 10/row): s<8 -> s^((row>>2)&3); s in {8,9}
//         -> 8 + ((s^(row>>2))&1). Makes QK-frag reads quarter-wave
//         conflict-free (was 4-way).
//      V: [80][64], slot (8/row): s ^ (row&7). Row stride 128 B would be
//         16-way conflicted unswizzled (G4); swizzle -> conflict-free.
//  - Q direct to registers (one load per block).
//  - PT (P transpose buffer) padded to stride 76: conflict-free writes.
//  - launch_bounds(256,4): VGPR cap 128, no spill (r1 lesson: (256,8) -> 32
//    VGPR + 80 MB scratch traffic).
// Varlen tile skipping as before (lens are multiples of 64 here).
__global__ __launch_bounds__(256, 4) void attn_mfma(
    const bf16* __restrict__ q, const bf16* __restrict__ k, const bf16* __restrict__ vt,
    const int* __restrict__ cu, bf16* __restrict__ o)
{
    __shared__ __align__(16) bf16 Ks[64*80];      // 10240 B, swizzled
    __shared__ __align__(16) bf16 VTs[80*64];     // 10240 B, swizzled
    __shared__ __align__(16) bf16 PTs[4][16*76];  // 9728 B, per-wave P^T

    // XCD-aware swizzle: xcd = n&7 constant for all 16 q-tiles of a (b,h).
    const int n  = blockIdx.x;
    const int g  = (n & 7) * 8 + (n >> 7);   // (b,h) group 0..63
    const int qt = (n >> 3) & 15;            // q-tile 0..15
    const int b  = g >> 4;
    const int h  = g & 15;

    const int tid  = threadIdx.x;
    const int lane = tid & 63, wv = tid >> 6;
    const int quad = lane >> 4, l15 = lane & 15;
    const int q0   = qt * 64;
    const int len  = cu[b + 1] - cu[b];

    const bool uniformq = (q0 >= len);
    const bool cleanlen = ((len & 63) == 0);
    const int  ktiles   = uniformq ? 16 : (cleanlen ? (len >> 6) : 16);
    const bool domask   = !uniformq && !cleanlen;

    bf16* PT = &PTs[wv][0];

    // Q fragments straight to registers (pre-roped, pre-scaled).
    // k-step 2 covers dims 64..95: quad>=2 (dims 80..95) zero-padded by mask.
    bf16x8 qf[3] = {};
    if (!uniformq) {
        const bf16* qrow = q + (size_t)(b*S_ + q0 + wv*16 + l15)*E_ + h*D_ + quad*8;
        qf[0] = *(const bf16x8*)(qrow);
        qf[1] = *(const bf16x8*)(qrow + 32);
        if (quad < 2) qf[2] = *(const bf16x8*)(qrow + 64);
    } else {
        // uniform path: PT = 1 for all 16 rows x 64 cols (written once)
        const bf16 one = f2b(1.0f);
        #pragma unroll
        for (int nt = 0; nt < 4; nt++)
            #pragma unroll
            for (int r = 0; r < 4; r++)
                PT[(quad*4 + r)*76 + nt*16 + l15] = one;
    }

    float m_r[4], l_r[4];
    #pragma unroll
    for (int r = 0; r < 4; r++) { m_r[r] = -1e30f; l_r[r] = 0.f; }
    f32x4 o_acc[5] = {};

    const bool q_full = (q0 + 64) <= len;

    // per-lane swizzled read slots
    const int u_  = l15 >> 2;
    const int s0r = quad ^ u_;            // K slot for ks=0; ks=1 is 4+s0r; ks=2 is 8+(s0r&1)
    const int sv0 = quad ^ (l15 & 7);     // V slot for ks=0; ks=1 is sv0^4

    for (int kt = 0; kt < ktiles; kt++) {
        __syncthreads();   // prev tile LDS reads done before restage
        if (!uniformq) {
            // ---- stage K tile: 640 x 16B chunks, swizzled global source
            #pragma unroll
            for (int i = 0; i < 3; i++) {
                int c = tid + i * 256;
                if (c < 640) {
                    int row = c / 10, s = c - row * 10;
                    int uu = (row >> 2) & 3;
                    int sg = (s < 8) ? (s ^ uu) : (8 + ((s ^ uu) & 1));
                    gload_lds16(k + (size_t)(b*S_ + kt*64 + row)*E_ + h*D_ + sg*8,
                                &Ks[c*8]);
                }
            }
        }
        // ---- stage V tile: 640 x 16B chunks, swizzled global source
        #pragma unroll
        for (int i = 0; i < 3; i++) {
            int c = tid + i * 256;
            if (c < 640) {
                int row = c >> 3, s = c & 7;
                int sg = s ^ (row & 7);
                gload_lds16(vt + ((size_t)(b*H_ + h)*D_ + row)*S_ + kt*64 + sg*8,
                            &VTs[c*8]);
            }
        }
        __syncthreads();   // drains vmcnt (global_load_lds) before reads

        if (!uniformq) {
            // ---- QK^T: 4 n-tiles x (2 full + 1 zero-padded) ksteps
            f32x4 s4[4];
            #pragma unroll
            for (int nt = 0; nt < 4; nt++) {
                const bf16* kr = Ks + (nt*16 + l15) * 80;
                bf16x8 kf0 = *(const bf16x8*)(kr + s0r*8);
                bf16x8 kf1 = *(const bf16x8*)(kr + 32 + s0r*8);
                bf16x8 kf2 = {};
                if (quad < 2) kf2 = *(const bf16x8*)(kr + 64 + (s0r & 1)*8);
                f32x4 a0 = {};
                a0 = __builtin_amdgcn_mfma_f32_16x16x32_bf16(qf[0], kf0, a0, 0, 0, 0);
                a0 = __builtin_amdgcn_mfma_f32_16x16x32_bf16(qf[1], kf1, a0, 0, 0, 0);
                a0 = __builtin_amdgcn_mfma_f32_16x16x32_bf16(qf[2], kf2, a0, 0, 0, 0);
                s4[nt] = a0;
            }

            // ---- online softmax (rows quad*4+r, wave-exclusive)
            float sv[4][4];
            if (!domask || (q_full && (kt*64 + 64) <= len)) {
                #pragma unroll
                for (int r = 0; r < 4; r++)
                    #pragma unroll
                    for (int nt = 0; nt < 4; nt++)
                        sv[nt][r] = s4[nt][r];
            } else {
                bool vk[4];
                #pragma unroll
                for (int nt = 0; nt < 4; nt++) vk[nt] = (kt*64 + nt*16 + l15) < len;
                #pragma unroll
                for (int r = 0; r < 4; r++) {
                    const bool vq = (q0 + wv*16 + quad*4 + r) < len;
                    #pragma unroll
                    for (int nt = 0; nt < 4; nt++)
                        sv[nt][r] = (vq && vk[nt]) ? s4[nt][r] : -1e9f;
                }
            }
            float rmax[4];
            #pragma unroll
            for (int r = 0; r < 4; r++)
                rmax[r] = fmaxf(fmaxf(sv[0][r], sv[1][r]), fmaxf(sv[2][r], sv[3][r]));
            #pragma unroll
            for (int st = 1; st < 16; st <<= 1)
                #pragma unroll
                for (int r = 0; r < 4; r++)
                    rmax[r] = fmaxf(rmax[r], __shfl_xor(rmax[r], st, 64));
            float mnew[4], alpha[4], rsum[4], p[4][4];
            #pragma unroll
            for (int r = 0; r < 4; r++) {
                mnew[r]  = fmaxf(m_r[r], rmax[r]);
                alpha[r] = __expf(m_r[r] - mnew[r]);
                float a = 0.f;
                #pragma unroll
                for (int nt = 0; nt < 4; nt++) { p[nt][r] = __expf(sv[nt][r] - mnew[r]); a += p[nt][r]; }
                rsum[r] = a;
            }
            #pragma unroll
            for (int st = 1; st < 16; st <<= 1)
                #pragma unroll
                for (int r = 0; r < 4; r++)
                    rsum[r] += __shfl_xor(rsum[r], st, 64);
            #pragma unroll
            for (int r = 0; r < 4; r++) {
                l_r[r] = l_r[r] * alpha[r] + rsum[r];
                m_r[r] = mnew[r];
            }
            #pragma unroll
            for (int dt = 0; dt < 5; dt++)
                #pragma unroll
                for (int r = 0; r < 4; r++)
                    o_acc[dt][r] *= alpha[r];
            // P (C-layout) -> PT (A-layout); same-wave LDS RAW, no barrier needed
            #pragma unroll
            for (int nt = 0; nt < 4; nt++)
                #pragma unroll
                for (int r = 0; r < 4; r++)
                    PT[(quad*4 + r)*76 + nt*16 + l15] = f2b(p[nt][r]);
        }

        // ---- PV: V B-frags from swizzled VTs
        bf16x8 pa0 = *(const bf16x8*)&PT[l15*76 + quad*8];
        bf16x8 pa1 = *(const bf16x8*)&PT[l15*76 + 32 + quad*8];
        #pragma unroll
        for (int dt = 0; dt < 5; dt++) {
            const bf16* vr = VTs + (dt*16 + l15) * 64;
            bf16x8 vf0 = *(const bf16x8*)(vr + sv0*8);
            bf16x8 vf1 = *(const bf16x8*)(vr + (sv0 ^ 4)*8);
            o_acc[dt] = __builtin_amdgcn_mfma_f32_16x16x32_bf16(pa0, vf0, o_acc[dt], 0, 0, 0);
            o_acc[dt] = __builtin_amdgcn_mfma_f32_16x16x32_bf16(pa1, vf1, o_acc[dt], 0, 0, 0);
        }
    }

    // ---- epilogue
    #pragma unroll
    for (int r = 0; r < 4; r++) {
        const float inv = uniformq ? (1.0f / 1024.0f) : (1.0f / l_r[r]);
        size_t row_g = (size_t)(b*S_ + q0 + wv*16 + quad*4 + r);
        #pragma unroll
        for (int dt = 0; dt < 5; dt++)
            o[row_g*E_ + h*D_ + dt*16 + l15] = f2b(o_acc[dt][r] * inv);
    }
}

extern "C" void kernel_launch(void* const* d_in, const int* in_sizes, int n_in,
                              void* d_out, int out_size, void* d_ws, size_t ws_size,
                              hipStream_t stream)
{
    const float* x    = (const float*)d_in[0];
    const int*   cu   = (const int*)  d_in[1];
    const float* cosp = (const float*)d_in[2];
    const float* sinp = (const float*)d_in[3];
    const float* wq   = (const float*)d_in[4];
    const float* bq   = (const float*)d_in[5];
    const float* wk   = (const float*)d_in[6];
    const float* bk   = (const float*)d_in[7];
    const float* wv   = (const float*)d_in[8];
    const float* bv   = (const float*)d_in[9];
    const float* wo   = (const float*)d_in[10];
    const float* bo   = (const float*)d_in[11];
    float* out = (float*)d_out;

    bf16* q   = (bf16*)d_ws;
    bf16* kk  = q   + (size_t)M_ * E_;
    bf16* vt  = kk  + (size_t)M_ * E_;   // transposed V: [B][H][D][S]
    bf16* ao  = vt  + (size_t)M_ * E_;
    bf16* xb  = ao  + (size_t)M_ * E_;
    bf16* wqb = xb  + (size_t)M_ * E_;
    bf16* wkb = wqb + (size_t)E_ * E_;
    bf16* wvb = wkb + (size_t)E_ * E_;
    bf16* wob = wvb + (size_t)E_ * E_;

    // 0) convert x + 4 weight matrices to bf16
    cvt_kernel<<<dim3(2560, 5), 256, 0, stream>>>(
        x, wq, wk, wv, wo, xb, wqb, wkb, wvb, wob, M_*E_, E_*E_);

    // 1) QKV projection (MFMA, BK=64), bias fused; V written transposed.
    mfma_gemm_bt<bf16, true><<<dim3(M_/128, 30), 256, 0, stream>>>(
        xb, wqb, wkb, wvb, bq, bk, bv, q, kk, vt, E_, E_, 10);

    // 1.5) one-shot RoPE on q (pre-scaled) and k, in place
    rope_kernel<<<2560, 256, 0, stream>>>(q, kk, cosp, sinp);

    // 2) MFMA flash attention (gload_lds staging, swizzled LDS, XCD swizzle)
    attn_mfma<<<1024, 256, 0, stream>>>(q, kk, vt, cu, ao);

    // 3) output projection (MFMA, BK=64), fp32 out, bias fused
    mfma_gemm_bt<float, false><<<dim3(M_/128, 10), 256, 0, stream>>>(
        ao, wob, wob, wob, bo, bo, bo, out, out, out, E_, E_, 10);
}

// Round 3
// 269.223 us; speedup vs baseline: 1.7136x; 1.0424x over previous
//
#include <hip/hip_runtime.h>
#include <hip/hip_bf16.h>

#define B_ 4
#define S_ 1024
#define E_ 1280
#define H_ 16
#define D_ 80
#define M_ (B_*S_)   // 4096
#define QBLK 128

typedef __hip_bfloat16 bf16;
using bf16x8 = __attribute__((ext_vector_type(8))) short;  // 8 bf16 = 4 VGPRs
using f32x4  = __attribute__((ext_vector_type(4))) float;  // MFMA C/D frag

__device__ __forceinline__ float b2f(bf16 x){ return __bfloat162float(x); }
__device__ __forceinline__ bf16  f2b(float x){ return __float2bfloat16(x); }
__device__ __forceinline__ void  stf(float* p, float v){ *p = v; }
__device__ __forceinline__ void  stf(bf16*  p, float v){ *p = f2b(v); }

__device__ __forceinline__ void gload_lds16(const void* g, void* l) {
    __builtin_amdgcn_global_load_lds(
        (const __attribute__((address_space(1))) unsigned int*)g,
        (__attribute__((address_space(3))) unsigned int*)l, 16, 0, 0);
}

// fp32 -> bf16 conversion, 8 elems/thread. blockIdx.y selects segment.
__global__ __launch_bounds__(256) void cvt_kernel(
    const float* __restrict__ s0, const float* __restrict__ s1,
    const float* __restrict__ s2, const float* __restrict__ s3,
    const float* __restrict__ s4,
    bf16* __restrict__ d0, bf16* __restrict__ d1, bf16* __restrict__ d2,
    bf16* __restrict__ d3, bf16* __restrict__ d4,
    int n0, int n1)
{
    const float* s; bf16* d; int n;
    switch (blockIdx.y) {
        case 0: s = s0; d = d0; n = n0; break;
        case 1: s = s1; d = d1; n = n1; break;
        case 2: s = s2; d = d2; n = n1; break;
        case 3: s = s3; d = d3; n = n1; break;
        default: s = s4; d = d4; n = n1; break;
    }
    int i = (blockIdx.x * 256 + threadIdx.x) * 8;
    if (i >= n) return;
    float4 a = *(const float4*)(s + i);
    float4 b = *(const float4*)(s + i + 4);
    bf16 t[8];
    t[0]=f2b(a.x); t[1]=f2b(a.y); t[2]=f2b(a.z); t[3]=f2b(a.w);
    t[4]=f2b(b.x); t[5]=f2b(b.y); t[6]=f2b(b.z); t[7]=f2b(b.w);
    *(uint4*)(d + i) = *(const uint4*)t;
}

// m97-style MFMA GEMM, BK=64 (two [128][32] LDS panels per operand).
// C[m,n] = sum_k A[m,k]*W[n,k] + bias[n]
// VT_OUT: mat==2 (V) stores transposed as VT[btok][h][d][key].
template<typename TC, bool VT_OUT>
__global__ __launch_bounds__(256) void mfma_gemm_bt(
    const bf16* __restrict__ A,
    const bf16* __restrict__ W0, const bf16* __restrict__ W1, const bf16* __restrict__ W2,
    const float* __restrict__ b0, const float* __restrict__ b1, const float* __restrict__ b2,
    TC* __restrict__ C0, TC* __restrict__ C1, TC* __restrict__ C2,
    int K, int N, int ntiles)
{
    const int mat = blockIdx.y / ntiles;
    const int bn  = (blockIdx.y % ntiles) * 128;
    const int bm  = blockIdx.x * 128;
    const bf16* W; const float* bias; TC* C;
    if (mat == 0)      { W = W0; bias = b0; C = C0; }
    else if (mat == 1) { W = W1; bias = b1; C = C1; }
    else               { W = W2; bias = b2; C = C2; }

    __shared__ bf16 As[2][128][32];   // panel p covers k0 + p*32 .. +32
    __shared__ bf16 Ws[2][128][32];

    const int tid  = threadIdx.x;
    const int lane = tid & 63;
    const int wv   = tid >> 6;
    const int wm   = (wv & 1) * 64;
    const int wn   = (wv >> 1) * 64;
    const int srow = wv * 16 + (lane >> 2);
    const int scol = (lane & 3) * 8;

    f32x4 acc[4][4] = {};

    for (int k0 = 0; k0 < K; k0 += 64) {
        __syncthreads();
        #pragma unroll
        for (int p = 0; p < 2; p++) {
            const int kc = k0 + p*32 + scol;
            gload_lds16(A + (size_t)(bm + srow)      * K + kc, &As[p][wv*16][0]);
            gload_lds16(A + (size_t)(bm + 64 + srow) * K + kc, &As[p][64 + wv*16][0]);
            gload_lds16(W + (size_t)(bn + srow)      * K + kc, &Ws[p][wv*16][0]);
            gload_lds16(W + (size_t)(bn + 64 + srow) * K + kc, &Ws[p][64 + wv*16][0]);
        }
        __syncthreads();

        const int fr = lane & 15;
        const int kq = (lane >> 4) * 8;
        #pragma unroll
        for (int p = 0; p < 2; p++) {
            bf16x8 af[4], wf[4];
            #pragma unroll
            for (int t = 0; t < 4; t++) {
                af[t] = *(const bf16x8*)&As[p][wm + t*16 + fr][kq];
                wf[t] = *(const bf16x8*)&Ws[p][wn + t*16 + fr][kq];
            }
            #pragma unroll
            for (int mt = 0; mt < 4; mt++)
                #pragma unroll
                for (int nt = 0; nt < 4; nt++)
                    acc[mt][nt] = __builtin_amdgcn_mfma_f32_16x16x32_bf16(
                        af[mt], wf[nt], acc[mt][nt], 0, 0, 0);
        }
    }

    const int col_l = lane & 15;
    const int row_l = (lane >> 4) * 4;

    if (VT_OUT && mat == 2) {
        const int btok = bm >> 10;
        const int keyb = (bm & 1023) + wm + row_l;
        #pragma unroll
        for (int nt = 0; nt < 4; nt++) {
            const int n = bn + wn + nt*16 + col_l;
            const float bv = bias[n];
            const int hh = n / 80, dd = n % 80;
            bf16* vbase = (bf16*)C + ((size_t)(btok*H_ + hh)*D_ + dd)*S_ + keyb;
            #pragma unroll
            for (int mt = 0; mt < 4; mt++) {
                union { bf16 h[4]; uint2 u; } t4;
                #pragma unroll
                for (int r = 0; r < 4; r++) t4.h[r] = f2b(acc[mt][nt][r] + bv);
                *(uint2*)&vbase[mt*16] = t4.u;
            }
        }
    } else {
        #pragma unroll
        for (int nt = 0; nt < 4; nt++) {
            const int n = bn + wn + nt*16 + col_l;
            const float bv = bias[n];
            #pragma unroll
            for (int mt = 0; mt < 4; mt++) {
                #pragma unroll
                for (int r = 0; r < 4; r++) {
                    const int m = bm + wm + mt*16 + row_l + r;
                    stf(&C[(size_t)m * N + n], acc[mt][nt][r] + bv);
                }
            }
        }
    }
}

// rope helper: lo=dims j..j+8 (j<40), hi=j+40.. ; out_lo = x1*c - x2*s, out_hi = x2*c + x1*s
__device__ __forceinline__ void rope8(const bf16* lo, const bf16* hi,
                                      const float* cp, const float* sp,
                                      float mul, uint4* out_lo, uint4* out_hi)
{
    union { uint4 u; bf16 h[8]; } li, hi_, lo_o, hi_o;
    li.u  = *(const uint4*)lo;
    hi_.u = *(const uint4*)hi;
    #pragma unroll
    for (int u = 0; u < 8; u++) {
        float x1 = b2f(li.h[u]), x2 = b2f(hi_.h[u]);
        float c = cp[u], s = sp[u];
        lo_o.h[u] = f2b((x1*c - x2*s) * mul);
        hi_o.h[u] = f2b((x2*c + x1*s) * mul);
    }
    *out_lo = lo_o.u;
    *out_hi = hi_o.u;
}

// One-shot in-place RoPE over q and k. Q additionally pre-scaled by 1/sqrt(80).
__global__ __launch_bounds__(256) void rope_kernel(
    bf16* __restrict__ qp, bf16* __restrict__ kp,
    const float* __restrict__ cosp, const float* __restrict__ sinp)
{
    int idx = blockIdx.x * 256 + threadIdx.x;
    const int NT = M_ * H_ * 5;   // 327680
    bf16* base; float mul;
    if (idx < NT) { base = qp; mul = 0.11180339887498949f; }
    else         { base = kp; mul = 1.0f; idx -= NT; }
    const int row = idx / 80;          // token 0..4095
    const int rem = idx - row * 80;
    const int h   = rem / 5;
    const int pc  = rem - h * 5;
    const int s   = row & (S_ - 1);
    bf16* p = base + (size_t)row * E_ + h * D_ + pc * 8;
    const float* cp = cosp + s * D_ + pc * 8;
    const float* sp = sinp + s * D_ + pc * 8;
    uint4 olo, ohi;
    rope8(p, p + 40, cp, sp, mul, &olo, &ohi);
    *(uint4*)p        = olo;
    *(uint4*)(p + 40) = ohi;
}

// MFMA flash attention v10:
//  - r2 lesson: conflicts=0 + staging VALU gone but dur unchanged -> the
//    bottleneck was the NON-PIPELINED stage->drain->compute loop (full L2/HBM
//    latency exposed per tile) + XCD work imbalance.
//  - v10: 128-row q-supertile per block (512 thr, 8 waves), double-buffered
//    K/V staging pipelined m97-style: issue stage(kt+1) BEFORE compute(kt),
//    ONE barrier per tile. The vmcnt(0) drain at the barrier lands after the
//    compute phase -> latency hidden.
//  - Balanced XCD mapping: XCD = n&7 = h&7 -> each XCD gets 2 heads of every
//    batch (equal work), and all 8 q-blocks of a (b,h) share one XCD's L2.
//  - Swizzled LDS layouts as v9 (swizzle global source; same XOR on reads):
//      K: [64][80] slot s<8 -> s^((row>>2)&3); s in {8,9} -> 8+((s^(row>>2))&1)
//      V: [80][64] slot s ^ (row&7)
//  - PT per-wave [16][76] (stride 76: conflict-free writes).
//  - LDS: 2*10240 + 2*10240 + 8*2432 = 60416 B -> exactly 2 blocks/CU,
//    grid 512 = 2/CU, zero residency tail.
// Varlen: lens are multiples of 128 here -> supertile fully valid or fully
// uniform; len%128!=0 falls back to full 16-tile masked path.
__global__ __launch_bounds__(512, 4) void attn_mfma(
    const bf16* __restrict__ q, const bf16* __restrict__ k, const bf16* __restrict__ vt,
    const int* __restrict__ cu, bf16* __restrict__ o)
{
    __shared__ __align__(16) bf16 Ks[2][64*80];    // 2 x 10240 B, swizzled
    __shared__ __align__(16) bf16 VTs[2][80*64];   // 2 x 10240 B, swizzled
    __shared__ __align__(16) bf16 PTs[8][16*76];   // 19456 B, per-wave P^T

    const int n  = blockIdx.x;                 // 512 blocks
    const int g  = ((n >> 6) << 3) | (n & 7);  // (b,h): XCD = n&7 = h&7
    const int qs = (n >> 3) & 7;               // q-supertile 0..7 (128 rows)
    const int b  = g >> 4;
    const int h  = g & 15;

    const int tid  = threadIdx.x;
    const int lane = tid & 63, wv = tid >> 6;  // wv 0..7
    const int quad = lane >> 4, l15 = lane & 15;
    const int q0   = qs * QBLK;
    const int len  = cu[b + 1] - cu[b];

    const bool uniformq = (q0 >= len);
    const bool clean    = ((len & (QBLK - 1)) == 0);
    const int  ktiles   = uniformq ? 16 : (clean ? (len >> 6) : 16);
    const bool domask   = !uniformq && !clean;

    bf16* PT = &PTs[wv][0];

    // Q fragments straight to registers (pre-roped, pre-scaled).
    // k-step 2 covers dims 64..95: quad>=2 (dims 80..95) zero-padded by mask.
    bf16x8 qf[3] = {};
    if (!uniformq) {
        const bf16* qrow = q + (size_t)(b*S_ + q0 + wv*16 + l15)*E_ + h*D_ + quad*8;
        qf[0] = *(const bf16x8*)(qrow);
        qf[1] = *(const bf16x8*)(qrow + 32);
        if (quad < 2) qf[2] = *(const bf16x8*)(qrow + 64);
    } else {
        // uniform path: PT = 1 for all 16 rows x 64 cols (written once)
        const bf16 one = f2b(1.0f);
        #pragma unroll
        for (int nt = 0; nt < 4; nt++)
            #pragma unroll
            for (int r = 0; r < 4; r++)
                PT[(quad*4 + r)*76 + nt*16 + l15] = one;
    }

    float m_r[4], l_r[4];
    #pragma unroll
    for (int r = 0; r < 4; r++) { m_r[r] = -1e30f; l_r[r] = 0.f; }
    f32x4 o_acc[5] = {};

    // per-lane swizzled read slots
    const int u_  = l15 >> 2;
    const int s0r = quad ^ u_;            // K slot ks=0; ks=1: +32; ks=2: &1
    const int sv0 = quad ^ (l15 & 7);     // V slot ks=0; ks=1: ^4

    // unified staging: chunks 0..639 = K tile (skipped if uniformq),
    // 640..1279 = V tile. 640 % 64 == 0 -> no wave straddles branches.
    auto stage = [&](int kt, int bf) {
        #pragma unroll
        for (int i = 0; i < 3; i++) {
            int c = tid + i * 512;
            if (c < 640) {
                if (!uniformq) {
                    int row = c / 10, s5 = c - row * 10;
                    int uu = (row >> 2) & 3;
                    int sg = (s5 < 8) ? (s5 ^ uu) : (8 + ((s5 ^ uu) & 1));
                    gload_lds16(k + (size_t)(b*S_ + kt*64 + row)*E_ + h*D_ + sg*8,
                                &Ks[bf][c*8]);
                }
            } else if (c < 1280) {
                int c2 = c - 640;
                int row = c2 >> 3, s5 = c2 & 7;
                int sg = s5 ^ (row & 7);
                gload_lds16(vt + ((size_t)(b*H_ + h)*D_ + row)*S_ + kt*64 + sg*8,
                            &VTs[bf][c2*8]);
            }
        }
    };

    stage(0, 0);
    __syncthreads();   // buf0 ready (vmcnt drained by barrier)

    const bool q_full = (q0 + 64) <= len;   // for masked fallback only

    for (int kt = 0; kt < ktiles; kt++) {
        const int cur = kt & 1;
        if (kt + 1 < ktiles) stage(kt + 1, cur ^ 1);   // loads fly during compute

        if (!uniformq) {
            // ---- QK^T: 4 n-tiles x (2 full + 1 zero-padded) ksteps
            f32x4 s4[4];
            #pragma unroll
            for (int nt = 0; nt < 4; nt++) {
                const bf16* kr = &Ks[cur][(nt*16 + l15) * 80];
                bf16x8 kf0 = *(const bf16x8*)(kr + s0r*8);
                bf16x8 kf1 = *(const bf16x8*)(kr + 32 + s0r*8);
                bf16x8 kf2 = {};
                if (quad < 2) kf2 = *(const bf16x8*)(kr + 64 + (s0r & 1)*8);
                f32x4 a0 = {};
                a0 = __builtin_amdgcn_mfma_f32_16x16x32_bf16(qf[0], kf0, a0, 0, 0, 0);
                a0 = __builtin_amdgcn_mfma_f32_16x16x32_bf16(qf[1], kf1, a0, 0, 0, 0);
                a0 = __builtin_amdgcn_mfma_f32_16x16x32_bf16(qf[2], kf2, a0, 0, 0, 0);
                s4[nt] = a0;
            }

            // ---- online softmax (rows quad*4+r, wave-exclusive)
            float sv[4][4];
            if (!domask || (q_full && (kt*64 + 64) <= len)) {
                #pragma unroll
                for (int r = 0; r < 4; r++)
                    #pragma unroll
                    for (int nt = 0; nt < 4; nt++)
                        sv[nt][r] = s4[nt][r];
            } else {
                bool vk[4];
                #pragma unroll
                for (int nt = 0; nt < 4; nt++) vk[nt] = (kt*64 + nt*16 + l15) < len;
                #pragma unroll
                for (int r = 0; r < 4; r++) {
                    const bool vq = (q0 + wv*16 + quad*4 + r) < len;
                    #pragma unroll
                    for (int nt = 0; nt < 4; nt++)
                        sv[nt][r] = (vq && vk[nt]) ? s4[nt][r] : -1e9f;
                }
            }
            float rmax[4];
            #pragma unroll
            for (int r = 0; r < 4; r++)
                rmax[r] = fmaxf(fmaxf(sv[0][r], sv[1][r]), fmaxf(sv[2][r], sv[3][r]));
            #pragma unroll
            for (int st = 1; st < 16; st <<= 1)
                #pragma unroll
                for (int r = 0; r < 4; r++)
                    rmax[r] = fmaxf(rmax[r], __shfl_xor(rmax[r], st, 64));
            float mnew[4], alpha[4], rsum[4], p[4][4];
            #pragma unroll
            for (int r = 0; r < 4; r++) {
                mnew[r]  = fmaxf(m_r[r], rmax[r]);
                alpha[r] = __expf(m_r[r] - mnew[r]);
                float a = 0.f;
                #pragma unroll
                for (int nt = 0; nt < 4; nt++) { p[nt][r] = __expf(sv[nt][r] - mnew[r]); a += p[nt][r]; }
                rsum[r] = a;
            }
            #pragma unroll
            for (int st = 1; st < 16; st <<= 1)
                #pragma unroll
                for (int r = 0; r < 4; r++)
                    rsum[r] += __shfl_xor(rsum[r], st, 64);
            #pragma unroll
            for (int r = 0; r < 4; r++) {
                l_r[r] = l_r[r] * alpha[r] + rsum[r];
                m_r[r] = mnew[r];
            }
            #pragma unroll
            for (int dt = 0; dt < 5; dt++)
                #pragma unroll
                for (int r = 0; r < 4; r++)
                    o_acc[dt][r] *= alpha[r];
            // P (C-layout) -> PT (A-layout); same-wave LDS RAW, no barrier needed
            #pragma unroll
            for (int nt = 0; nt < 4; nt++)
                #pragma unroll
                for (int r = 0; r < 4; r++)
                    PT[(quad*4 + r)*76 + nt*16 + l15] = f2b(p[nt][r]);
        }

        // ---- PV: V B-frags from swizzled VTs[cur]
        bf16x8 pa0 = *(const bf16x8*)&PT[l15*76 + quad*8];
        bf16x8 pa1 = *(const bf16x8*)&PT[l15*76 + 32 + quad*8];
        #pragma unroll
        for (int dt = 0; dt < 5; dt++) {
            const bf16* vr = &VTs[cur][(dt*16 + l15) * 64];
            bf16x8 vf0 = *(const bf16x8*)(vr + sv0*8);
            bf16x8 vf1 = *(const bf16x8*)(vr + (sv0 ^ 4)*8);
            o_acc[dt] = __builtin_amdgcn_mfma_f32_16x16x32_bf16(pa0, vf0, o_acc[dt], 0, 0, 0);
            o_acc[dt] = __builtin_amdgcn_mfma_f32_16x16x32_bf16(pa1, vf1, o_acc[dt], 0, 0, 0);
        }
        __syncthreads();   // all reads of buf[cur] done; buf[cur^1] loads drained
    }

    // ---- epilogue
    #pragma unroll
    for (int r = 0; r < 4; r++) {
        const float inv = uniformq ? (1.0f / 1024.0f) : (1.0f / l_r[r]);
        size_t row_g = (size_t)(b*S_ + q0 + wv*16 + quad*4 + r);
        #pragma unroll
        for (int dt = 0; dt < 5; dt++)
            o[row_g*E_ + h*D_ + dt*16 + l15] = f2b(o_acc[dt][r] * inv);
    }
}

extern "C" void kernel_launch(void* const* d_in, const int* in_sizes, int n_in,
                              void* d_out, int out_size, void* d_ws, size_t ws_size,
                              hipStream_t stream)
{
    const float* x    = (const float*)d_in[0];
    const int*   cu   = (const int*)  d_in[1];
    const float* cosp = (const float*)d_in[2];
    const float* sinp = (const float*)d_in[3];
    const float* wq   = (const float*)d_in[4];
    const float* bq   = (const float*)d_in[5];
    const float* wk   = (const float*)d_in[6];
    const float* bk   = (const float*)d_in[7];
    const float* wv   = (const float*)d_in[8];
    const float* bv   = (const float*)d_in[9];
    const float* wo   = (const float*)d_in[10];
    const float* bo   = (const float*)d_in[11];
    float* out = (float*)d_out;

    bf16* q   = (bf16*)d_ws;
    bf16* kk  = q   + (size_t)M_ * E_;
    bf16* vt  = kk  + (size_t)M_ * E_;   // transposed V: [B][H][D][S]
    bf16* ao  = vt  + (size_t)M_ * E_;
    bf16* xb  = ao  + (size_t)M_ * E_;
    bf16* wqb = xb  + (size_t)M_ * E_;
    bf16* wkb = wqb + (size_t)E_ * E_;
    bf16* wvb = wkb + (size_t)E_ * E_;
    bf16* wob = wvb + (size_t)E_ * E_;

    // 0) convert x + 4 weight matrices to bf16
    cvt_kernel<<<dim3(2560, 5), 256, 0, stream>>>(
        x, wq, wk, wv, wo, xb, wqb, wkb, wvb, wob, M_*E_, E_*E_);

    // 1) QKV projection (MFMA, BK=64), bias fused; V written transposed.
    mfma_gemm_bt<bf16, true><<<dim3(M_/128, 30), 256, 0, stream>>>(
        xb, wqb, wkb, wvb, bq, bk, bv, q, kk, vt, E_, E_, 10);

    // 1.5) one-shot RoPE on q (pre-scaled) and k, in place
    rope_kernel<<<2560, 256, 0, stream>>>(q, kk, cosp, sinp);

    // 2) MFMA flash attention v10 (pipelined dbuf staging, 128-row blocks,
    //    balanced XCD swizzle)
    attn_mfma<<<512, 512, 0, stream>>>(q, kk, vt, cu, ao);

    // 3) output projection (MFMA, BK=64), fp32 out, bias fused
    mfma_gemm_bt<float, false><<<dim3(M_/128, 10), 256, 0, stream>>>(
        ao, wob, wob, wob, bo, bo, bo, out, out, out, E_, E_, 10);
}

// Round 4
// 254.531 us; speedup vs baseline: 1.8126x; 1.0577x over previous
//
#include <hip/hip_runtime.h>
#include <hip/hip_bf16.h>

#define B_ 4
#define S_ 1024
#define E_ 1280
#define H_ 16
#define D_ 80
#define M_ (B_*S_)   // 4096
#define QBLK 128

typedef __hip_bfloat16 bf16;
using bf16x8 = __attribute__((ext_vector_type(8))) short;  // 8 bf16 = 4 VGPRs
using f32x4  = __attribute__((ext_vector_type(4))) float;  // MFMA C/D frag

__device__ __forceinline__ float b2f(bf16 x){ return __bfloat162float(x); }
__device__ __forceinline__ bf16  f2b(float x){ return __float2bfloat16(x); }
__device__ __forceinline__ void  stf(float* p, float v){ *p = v; }
__device__ __forceinline__ void  stf(bf16*  p, float v){ *p = f2b(v); }

__device__ __forceinline__ void gload_lds16(const void* g, void* l) {
    __builtin_amdgcn_global_load_lds(
        (const __attribute__((address_space(1))) unsigned int*)g,
        (__attribute__((address_space(3))) unsigned int*)l, 16, 0, 0);
}

// 8-phase sync helpers (rule #18: sched_barrier(0) after inline waitcnt)
__device__ __forceinline__ void ph_begin() {
    __builtin_amdgcn_s_barrier();
    asm volatile("s_waitcnt lgkmcnt(0)" ::: "memory");
    __builtin_amdgcn_sched_barrier(0);
    __builtin_amdgcn_s_setprio(1);
}
__device__ __forceinline__ void ph_end() {
    __builtin_amdgcn_s_setprio(0);
    __builtin_amdgcn_sched_barrier(0);
    __builtin_amdgcn_s_barrier();
}
__device__ __forceinline__ void ph_end_vm6() {
    __builtin_amdgcn_s_setprio(0);
    __builtin_amdgcn_sched_barrier(0);
    asm volatile("s_waitcnt vmcnt(6)" ::: "memory");
    __builtin_amdgcn_s_barrier();
}
__device__ __forceinline__ void ph_end_vm0() {
    __builtin_amdgcn_s_setprio(0);
    __builtin_amdgcn_sched_barrier(0);
    asm volatile("s_waitcnt vmcnt(0)" ::: "memory");
    __builtin_amdgcn_s_barrier();
}

// fp32 -> bf16 conversion, 8 elems/thread. blockIdx.y selects segment.
__global__ __launch_bounds__(256) void cvt_kernel(
    const float* __restrict__ s0, const float* __restrict__ s1,
    const float* __restrict__ s2, const float* __restrict__ s3,
    const float* __restrict__ s4,
    bf16* __restrict__ d0, bf16* __restrict__ d1, bf16* __restrict__ d2,
    bf16* __restrict__ d3, bf16* __restrict__ d4,
    int n0, int n1)
{
    const float* s; bf16* d; int n;
    switch (blockIdx.y) {
        case 0: s = s0; d = d0; n = n0; break;
        case 1: s = s1; d = d1; n = n1; break;
        case 2: s = s2; d = d2; n = n1; break;
        case 3: s = s3; d = d3; n = n1; break;
        default: s = s4; d = d4; n = n1; break;
    }
    int i = (blockIdx.x * 256 + threadIdx.x) * 8;
    if (i >= n) return;
    float4 a = *(const float4*)(s + i);
    float4 b = *(const float4*)(s + i + 4);
    bf16 t[8];
    t[0]=f2b(a.x); t[1]=f2b(a.y); t[2]=f2b(a.z); t[3]=f2b(a.w);
    t[4]=f2b(b.x); t[5]=f2b(b.y); t[6]=f2b(b.z); t[7]=f2b(b.w);
    *(uint4*)(d + i) = *(const uint4*)t;
}

// ============================================================================
// QKV projection: 256x256 8-phase MFMA GEMM (T2+T3+T4+T5 per guide §5).
// C[m,n] = sum_k A[m,k]*W[n,k] + bias[n]; N = 3840 (q|k|v), K = 1280.
// - 512 thr (8 waves, 2M x 4N), per-wave output 128x64, acc[8][4] f32x4.
// - LDS 128 KiB: 2 buf x {A,B} x 2 half x [128][64] bf16. Tile j -> buf j&1.
// - Granule swizzle g ^= (row&7) (G4 formula): b128 frag reads hit all 32
//   banks uniformly (floor). Applied on pre-swizzled GLOBAL src + ds_read.
// - 8 phases/iter (2 K-tiles): per phase {ds-subtile, 1 half-tile stage,
//   barrier, lgkmcnt(0), setprio(1), 16 MFMA, setprio(0), barrier}.
//   Stage slots: ph1:A1(j+1) ph3:B0(j+2) ph4:B1+A0(j+2)+vmcnt(6)
//   ph5:A1(j+2) ph7:B0(j+3) ph8:B1+A0(j+3)+vmcnt(6).
//   Derivation checked: every region overwritten >=1 barrier after its last
//   read; every read covered by a prior vmcnt(6) drain (steady state keeps
//   exactly 6 loads = 3 half-tiles in flight). Last iter: vmcnt(0) at ph4.
// - mat 2 (V) written transposed VT[btok][h][d][key].
// ============================================================================
__global__ __launch_bounds__(512, 2) void qkv_gemm_8ph(
    const bf16* __restrict__ A,
    const bf16* __restrict__ W0, const bf16* __restrict__ W1, const bf16* __restrict__ W2,
    const float* __restrict__ b0, const float* __restrict__ b1, const float* __restrict__ b2,
    bf16* __restrict__ Cq, bf16* __restrict__ Ck, bf16* __restrict__ Cv)
{
    constexpr int K = 1280;
    constexpr int NITER = K / 128;   // 10 iterations, 2 K-tiles each

    __shared__ __align__(16) bf16 Asm[2][2][128*64];   // [buf][half][row*64+col]
    __shared__ __align__(16) bf16 Bsm[2][2][128*64];

    const int bm  = blockIdx.x * 256;
    const int ny  = blockIdx.y;            // 0..14
    const int mat = ny / 5;
    const int bn  = (ny % 5) * 256;        // col base within matrix
    const bf16*  W    = (mat == 0) ? W0 : (mat == 1) ? W1 : W2;
    const float* bias = (mat == 0) ? b0 : (mat == 1) ? b1 : b2;

    const int tid  = threadIdx.x;
    const int lane = tid & 63, wv = tid >> 6;
    const int wm = wv >> 2, wn = wv & 3;        // wave tile: rows wm*128, cols wn*64
    const int quad = lane >> 4, l15 = lane & 15;

    // ---- staging: 1024 chunks of 16B per half-tile, 2 per thread.
    // chunk c: row=c>>3, lds granule g'=c&7 holds global granule g'^(row&7).
    auto stageA = [&](int j_, int half) {
        #pragma unroll
        for (int i = 0; i < 2; i++) {
            const int c   = tid + i*512;
            const int row = c >> 3;
            const int g   = (c & 7) ^ (row & 7);
            gload_lds16(A + (size_t)(bm + half*128 + row) * K + j_*64 + g*8,
                        &Asm[j_ & 1][half][(wv*64 + i*512) * 8]);
        }
    };
    auto stageB = [&](int j_, int half) {
        #pragma unroll
        for (int i = 0; i < 2; i++) {
            const int c   = tid + i*512;
            const int row = c >> 3;
            const int g   = (c & 7) ^ (row & 7);
            gload_lds16(W + (size_t)(bn + half*128 + row) * K + j_*64 + g*8,
                        &Bsm[j_ & 1][half][(wv*64 + i*512) * 8]);
        }
    };
    // ---- fragment reads (granule (quad|ks<<2) ^ (row&7); row&7 == l15&7)
    auto lda = [&](int bf, int mt, int ks) -> bf16x8 {
        const int r = mt*16 + l15;
        return *(const bf16x8*)&Asm[bf][wm][r*64 + (((quad + ks*4) ^ (r & 7)) << 3)];
    };
    auto ldb = [&](int bf, int nt, int ks) -> bf16x8 {
        const int r = (wn & 1)*64 + nt*16 + l15;
        return *(const bf16x8*)&Bsm[bf][wn >> 1][r*64 + (((quad + ks*4) ^ (r & 7)) << 3)];
    };

    f32x4 acc[8][4] = {};
    bf16x8 a[4][2], bA[2][2], bB[2][2];

#define MFMA_Q(MT0, NT0, BB_) do { \
    _Pragma("unroll") for (int mt_ = 0; mt_ < 4; mt_++) \
    _Pragma("unroll") for (int nt_ = 0; nt_ < 2; nt_++) \
    _Pragma("unroll") for (int ks_ = 0; ks_ < 2; ks_++) \
        acc[(MT0)+mt_][(NT0)+nt_] = __builtin_amdgcn_mfma_f32_16x16x32_bf16( \
            a[mt_][ks_], BB_[nt_][ks_], acc[(MT0)+mt_][(NT0)+nt_], 0, 0, 0); \
} while (0)

    // ---- prologue: tiles 0 (buf0) and 1 (buf1) fully staged, drained
    stageA(0, 0); stageA(0, 1); stageB(0, 0); stageB(0, 1);
    stageA(1, 0); stageA(1, 1); stageB(1, 0); stageB(1, 1);
    __syncthreads();

    for (int t = 0; t < NITER; t++) {
        const int  j  = 2*t;
        const bool pf = (t + 1 < NITER);

        // phase 1: ds a03+b01 (buf0); stage A1(j+1)
        #pragma unroll
        for (int mt = 0; mt < 4; mt++) { a[mt][0] = lda(0, mt, 0); a[mt][1] = lda(0, mt, 1); }
        #pragma unroll
        for (int nt = 0; nt < 2; nt++) { bA[nt][0] = ldb(0, nt, 0); bA[nt][1] = ldb(0, nt, 1); }
        stageA(j+1, 1);
        ph_begin(); MFMA_Q(0, 0, bA); ph_end();

        // phase 2: ds b23 (buf0)
        #pragma unroll
        for (int nt = 0; nt < 2; nt++) { bB[nt][0] = ldb(0, 2+nt, 0); bB[nt][1] = ldb(0, 2+nt, 1); }
        ph_begin(); MFMA_Q(0, 2, bB); ph_end();

        // phase 3: ds a47 (buf0); stage B0(j+2)
        #pragma unroll
        for (int mt = 0; mt < 4; mt++) { a[mt][0] = lda(0, 4+mt, 0); a[mt][1] = lda(0, 4+mt, 1); }
        if (pf) stageB(j+2, 0);
        ph_begin(); MFMA_Q(4, 0, bA); ph_end();

        // phase 4: stage B1(j+2)+A0(j+2); vmcnt
        if (pf) { stageB(j+2, 1); stageA(j+2, 0); }
        ph_begin(); MFMA_Q(4, 2, bB);
        if (pf) ph_end_vm6(); else ph_end_vm0();

        // phase 5: ds a03+b01 (buf1); stage A1(j+2)
        #pragma unroll
        for (int mt = 0; mt < 4; mt++) { a[mt][0] = lda(1, mt, 0); a[mt][1] = lda(1, mt, 1); }
        #pragma unroll
        for (int nt = 0; nt < 2; nt++) { bA[nt][0] = ldb(1, nt, 0); bA[nt][1] = ldb(1, nt, 1); }
        if (pf) stageA(j+2, 1);
        ph_begin(); MFMA_Q(0, 0, bA); ph_end();

        // phase 6: ds b23 (buf1)
        #pragma unroll
        for (int nt = 0; nt < 2; nt++) { bB[nt][0] = ldb(1, 2+nt, 0); bB[nt][1] = ldb(1, 2+nt, 1); }
        ph_begin(); MFMA_Q(0, 2, bB); ph_end();

        // phase 7: ds a47 (buf1); stage B0(j+3)
        #pragma unroll
        for (int mt = 0; mt < 4; mt++) { a[mt][0] = lda(1, 4+mt, 0); a[mt][1] = lda(1, 4+mt, 1); }
        if (pf) stageB(j+3, 0);
        ph_begin(); MFMA_Q(4, 0, bA); ph_end();

        // phase 8: stage B1(j+3)+A0(j+3); vmcnt(6)
        if (pf) { stageB(j+3, 1); stageA(j+3, 0); }
        ph_begin(); MFMA_Q(4, 2, bB); ph_end_vm6();
    }
#undef MFMA_Q

    // ---- epilogue
    if (mat < 2) {
        bf16* C = (mat == 0) ? Cq : Ck;
        #pragma unroll
        for (int nt = 0; nt < 4; nt++) {
            const int ncol = bn + wn*64 + nt*16 + l15;
            const float bv = bias[ncol];
            #pragma unroll
            for (int mt = 0; mt < 8; mt++) {
                const int m0 = bm + wm*128 + mt*16 + quad*4;
                #pragma unroll
                for (int r = 0; r < 4; r++)
                    C[(size_t)(m0 + r) * E_ + ncol] = f2b(acc[mt][nt][r] + bv);
            }
        }
    } else {
        #pragma unroll
        for (int nt = 0; nt < 4; nt++) {
            const int ncol = bn + wn*64 + nt*16 + l15;
            const float bv = bias[ncol];
            const int hh = ncol / 80, dd = ncol % 80;
            #pragma unroll
            for (int mt = 0; mt < 8; mt++) {
                const int m0  = bm + wm*128 + mt*16 + quad*4;
                const int btok = m0 >> 10;
                const int key  = m0 & 1023;
                union { bf16 h[4]; uint2 u; } t4;
                #pragma unroll
                for (int r = 0; r < 4; r++) t4.h[r] = f2b(acc[mt][nt][r] + bv);
                *(uint2*)&Cv[((size_t)(btok*H_ + hh)*D_ + dd)*S_ + key] = t4.u;
            }
        }
    }
}

// m97-style MFMA GEMM, BK=64 (two [128][32] LDS panels per operand).
// Used for the output projection only.
template<typename TC, bool VT_OUT>
__global__ __launch_bounds__(256) void mfma_gemm_bt(
    const bf16* __restrict__ A,
    const bf16* __restrict__ W0, const bf16* __restrict__ W1, const bf16* __restrict__ W2,
    const float* __restrict__ b0, const float* __restrict__ b1, const float* __restrict__ b2,
    TC* __restrict__ C0, TC* __restrict__ C1, TC* __restrict__ C2,
    int K, int N, int ntiles)
{
    const int mat = blockIdx.y / ntiles;
    const int bn  = (blockIdx.y % ntiles) * 128;
    const int bm  = blockIdx.x * 128;
    const bf16* W; const float* bias; TC* C;
    if (mat == 0)      { W = W0; bias = b0; C = C0; }
    else if (mat == 1) { W = W1; bias = b1; C = C1; }
    else               { W = W2; bias = b2; C = C2; }

    __shared__ bf16 As[2][128][32];
    __shared__ bf16 Ws[2][128][32];

    const int tid  = threadIdx.x;
    const int lane = tid & 63;
    const int wv   = tid >> 6;
    const int wm   = (wv & 1) * 64;
    const int wn   = (wv >> 1) * 64;
    const int srow = wv * 16 + (lane >> 2);
    const int scol = (lane & 3) * 8;

    f32x4 acc[4][4] = {};

    for (int k0 = 0; k0 < K; k0 += 64) {
        __syncthreads();
        #pragma unroll
        for (int p = 0; p < 2; p++) {
            const int kc = k0 + p*32 + scol;
            gload_lds16(A + (size_t)(bm + srow)      * K + kc, &As[p][wv*16][0]);
            gload_lds16(A + (size_t)(bm + 64 + srow) * K + kc, &As[p][64 + wv*16][0]);
            gload_lds16(W + (size_t)(bn + srow)      * K + kc, &Ws[p][wv*16][0]);
            gload_lds16(W + (size_t)(bn + 64 + srow) * K + kc, &Ws[p][64 + wv*16][0]);
        }
        __syncthreads();

        const int fr = lane & 15;
        const int kq = (lane >> 4) * 8;
        #pragma unroll
        for (int p = 0; p < 2; p++) {
            bf16x8 af[4], wf[4];
            #pragma unroll
            for (int t = 0; t < 4; t++) {
                af[t] = *(const bf16x8*)&As[p][wm + t*16 + fr][kq];
                wf[t] = *(const bf16x8*)&Ws[p][wn + t*16 + fr][kq];
            }
            #pragma unroll
            for (int mt = 0; mt < 4; mt++)
                #pragma unroll
                for (int nt = 0; nt < 4; nt++)
                    acc[mt][nt] = __builtin_amdgcn_mfma_f32_16x16x32_bf16(
                        af[mt], wf[nt], acc[mt][nt], 0, 0, 0);
        }
    }

    const int col_l = lane & 15;
    const int row_l = (lane >> 4) * 4;

    if (VT_OUT && mat == 2) {
        const int btok = bm >> 10;
        const int keyb = (bm & 1023) + wm + row_l;
        #pragma unroll
        for (int nt = 0; nt < 4; nt++) {
            const int n = bn + wn + nt*16 + col_l;
            const float bv = bias[n];
            const int hh = n / 80, dd = n % 80;
            bf16* vbase = (bf16*)C + ((size_t)(btok*H_ + hh)*D_ + dd)*S_ + keyb;
            #pragma unroll
            for (int mt = 0; mt < 4; mt++) {
                union { bf16 h[4]; uint2 u; } t4;
                #pragma unroll
                for (int r = 0; r < 4; r++) t4.h[r] = f2b(acc[mt][nt][r] + bv);
                *(uint2*)&vbase[mt*16] = t4.u;
            }
        }
    } else {
        #pragma unroll
        for (int nt = 0; nt < 4; nt++) {
            const int n = bn + wn + nt*16 + col_l;
            const float bv = bias[n];
            #pragma unroll
            for (int mt = 0; mt < 4; mt++) {
                #pragma unroll
                for (int r = 0; r < 4; r++) {
                    const int m = bm + wm + mt*16 + row_l + r;
                    stf(&C[(size_t)m * N + n], acc[mt][nt][r] + bv);
                }
            }
        }
    }
}

// rope helper
__device__ __forceinline__ void rope8(const bf16* lo, const bf16* hi,
                                      const float* cp, const float* sp,
                                      float mul, uint4* out_lo, uint4* out_hi)
{
    union { uint4 u; bf16 h[8]; } li, hi_, lo_o, hi_o;
    li.u  = *(const uint4*)lo;
    hi_.u = *(const uint4*)hi;
    #pragma unroll
    for (int u = 0; u < 8; u++) {
        float x1 = b2f(li.h[u]), x2 = b2f(hi_.h[u]);
        float c = cp[u], s = sp[u];
        lo_o.h[u] = f2b((x1*c - x2*s) * mul);
        hi_o.h[u] = f2b((x2*c + x1*s) * mul);
    }
    *out_lo = lo_o.u;
    *out_hi = hi_o.u;
}

// One-shot in-place RoPE over q and k. Q additionally pre-scaled by 1/sqrt(80).
__global__ __launch_bounds__(256) void rope_kernel(
    bf16* __restrict__ qp, bf16* __restrict__ kp,
    const float* __restrict__ cosp, const float* __restrict__ sinp)
{
    int idx = blockIdx.x * 256 + threadIdx.x;
    const int NT = M_ * H_ * 5;   // 327680
    bf16* base; float mul;
    if (idx < NT) { base = qp; mul = 0.11180339887498949f; }
    else         { base = kp; mul = 1.0f; idx -= NT; }
    const int row = idx / 80;
    const int rem = idx - row * 80;
    const int h   = rem / 5;
    const int pc  = rem - h * 5;
    const int s   = row & (S_ - 1);
    bf16* p = base + (size_t)row * E_ + h * D_ + pc * 8;
    const float* cp = cosp + s * D_ + pc * 8;
    const float* sp = sinp + s * D_ + pc * 8;
    uint4 olo, ohi;
    rope8(p, p + 40, cp, sp, mul, &olo, &ohi);
    *(uint4*)p        = olo;
    *(uint4*)(p + 40) = ohi;
}

// MFMA flash attention v10 (unchanged from r3 — no longer the top dispatch).
__global__ __launch_bounds__(512, 4) void attn_mfma(
    const bf16* __restrict__ q, const bf16* __restrict__ k, const bf16* __restrict__ vt,
    const int* __restrict__ cu, bf16* __restrict__ o)
{
    __shared__ __align__(16) bf16 Ks[2][64*80];
    __shared__ __align__(16) bf16 VTs[2][80*64];
    __shared__ __align__(16) bf16 PTs[8][16*76];

    const int n  = blockIdx.x;
    const int g  = ((n >> 6) << 3) | (n & 7);
    const int qs = (n >> 3) & 7;
    const int b  = g >> 4;
    const int h  = g & 15;

    const int tid  = threadIdx.x;
    const int lane = tid & 63, wv = tid >> 6;
    const int quad = lane >> 4, l15 = lane & 15;
    const int q0   = qs * QBLK;
    const int len  = cu[b + 1] - cu[b];

    const bool uniformq = (q0 >= len);
    const bool clean    = ((len & (QBLK - 1)) == 0);
    const int  ktiles   = uniformq ? 16 : (clean ? (len >> 6) : 16);
    const bool domask   = !uniformq && !clean;

    bf16* PT = &PTs[wv][0];

    bf16x8 qf[3] = {};
    if (!uniformq) {
        const bf16* qrow = q + (size_t)(b*S_ + q0 + wv*16 + l15)*E_ + h*D_ + quad*8;
        qf[0] = *(const bf16x8*)(qrow);
        qf[1] = *(const bf16x8*)(qrow + 32);
        if (quad < 2) qf[2] = *(const bf16x8*)(qrow + 64);
    } else {
        const bf16 one = f2b(1.0f);
        #pragma unroll
        for (int nt = 0; nt < 4; nt++)
            #pragma unroll
            for (int r = 0; r < 4; r++)
                PT[(quad*4 + r)*76 + nt*16 + l15] = one;
    }

    float m_r[4], l_r[4];
    #pragma unroll
    for (int r = 0; r < 4; r++) { m_r[r] = -1e30f; l_r[r] = 0.f; }
    f32x4 o_acc[5] = {};

    const int u_  = l15 >> 2;
    const int s0r = quad ^ u_;
    const int sv0 = quad ^ (l15 & 7);

    auto stage = [&](int kt, int bf) {
        #pragma unroll
        for (int i = 0; i < 3; i++) {
            int c = tid + i * 512;
            if (c < 640) {
                if (!uniformq) {
                    int row = c / 10, s5 = c - row * 10;
                    int uu = (row >> 2) & 3;
                    int sg = (s5 < 8) ? (s5 ^ uu) : (8 + ((s5 ^ uu) & 1));
                    gload_lds16(k + (size_t)(b*S_ + kt*64 + row)*E_ + h*D_ + sg*8,
                                &Ks[bf][c*8]);
                }
            } else if (c < 1280) {
                int c2 = c - 640;
                int row = c2 >> 3, s5 = c2 & 7;
                int sg = s5 ^ (row & 7);
                gload_lds16(vt + ((size_t)(b*H_ + h)*D_ + row)*S_ + kt*64 + sg*8,
                            &VTs[bf][c2*8]);
            }
        }
    };

    stage(0, 0);
    __syncthreads();

    const bool q_full = (q0 + 64) <= len;

    for (int kt = 0; kt < ktiles; kt++) {
        const int cur = kt & 1;
        if (kt + 1 < ktiles) stage(kt + 1, cur ^ 1);

        if (!uniformq) {
            f32x4 s4[4];
            #pragma unroll
            for (int nt = 0; nt < 4; nt++) {
                const bf16* kr = &Ks[cur][(nt*16 + l15) * 80];
                bf16x8 kf0 = *(const bf16x8*)(kr + s0r*8);
                bf16x8 kf1 = *(const bf16x8*)(kr + 32 + s0r*8);
                bf16x8 kf2 = {};
                if (quad < 2) kf2 = *(const bf16x8*)(kr + 64 + (s0r & 1)*8);
                f32x4 a0 = {};
                a0 = __builtin_amdgcn_mfma_f32_16x16x32_bf16(qf[0], kf0, a0, 0, 0, 0);
                a0 = __builtin_amdgcn_mfma_f32_16x16x32_bf16(qf[1], kf1, a0, 0, 0, 0);
                a0 = __builtin_amdgcn_mfma_f32_16x16x32_bf16(qf[2], kf2, a0, 0, 0, 0);
                s4[nt] = a0;
            }

            float sv[4][4];
            if (!domask || (q_full && (kt*64 + 64) <= len)) {
                #pragma unroll
                for (int r = 0; r < 4; r++)
                    #pragma unroll
                    for (int nt = 0; nt < 4; nt++)
                        sv[nt][r] = s4[nt][r];
            } else {
                bool vk[4];
                #pragma unroll
                for (int nt = 0; nt < 4; nt++) vk[nt] = (kt*64 + nt*16 + l15) < len;
                #pragma unroll
                for (int r = 0; r < 4; r++) {
                    const bool vq = (q0 + wv*16 + quad*4 + r) < len;
                    #pragma unroll
                    for (int nt = 0; nt < 4; nt++)
                        sv[nt][r] = (vq && vk[nt]) ? s4[nt][r] : -1e9f;
                }
            }
            float rmax[4];
            #pragma unroll
            for (int r = 0; r < 4; r++)
                rmax[r] = fmaxf(fmaxf(sv[0][r], sv[1][r]), fmaxf(sv[2][r], sv[3][r]));
            #pragma unroll
            for (int st = 1; st < 16; st <<= 1)
                #pragma unroll
                for (int r = 0; r < 4; r++)
                    rmax[r] = fmaxf(rmax[r], __shfl_xor(rmax[r], st, 64));
            float mnew[4], alpha[4], rsum[4], p[4][4];
            #pragma unroll
            for (int r = 0; r < 4; r++) {
                mnew[r]  = fmaxf(m_r[r], rmax[r]);
                alpha[r] = __expf(m_r[r] - mnew[r]);
                float a = 0.f;
                #pragma unroll
                for (int nt = 0; nt < 4; nt++) { p[nt][r] = __expf(sv[nt][r] - mnew[r]); a += p[nt][r]; }
                rsum[r] = a;
            }
            #pragma unroll
            for (int st = 1; st < 16; st <<= 1)
                #pragma unroll
                for (int r = 0; r < 4; r++)
                    rsum[r] += __shfl_xor(rsum[r], st, 64);
            #pragma unroll
            for (int r = 0; r < 4; r++) {
                l_r[r] = l_r[r] * alpha[r] + rsum[r];
                m_r[r] = mnew[r];
            }
            #pragma unroll
            for (int dt = 0; dt < 5; dt++)
                #pragma unroll
                for (int r = 0; r < 4; r++)
                    o_acc[dt][r] *= alpha[r];
            #pragma unroll
            for (int nt = 0; nt < 4; nt++)
                #pragma unroll
                for (int r = 0; r < 4; r++)
                    PT[(quad*4 + r)*76 + nt*16 + l15] = f2b(p[nt][r]);
        }

        bf16x8 pa0 = *(const bf16x8*)&PT[l15*76 + quad*8];
        bf16x8 pa1 = *(const bf16x8*)&PT[l15*76 + 32 + quad*8];
        #pragma unroll
        for (int dt = 0; dt < 5; dt++) {
            const bf16* vr = &VTs[cur][(dt*16 + l15) * 64];
            bf16x8 vf0 = *(const bf16x8*)(vr + sv0*8);
            bf16x8 vf1 = *(const bf16x8*)(vr + (sv0 ^ 4)*8);
            o_acc[dt] = __builtin_amdgcn_mfma_f32_16x16x32_bf16(pa0, vf0, o_acc[dt], 0, 0, 0);
            o_acc[dt] = __builtin_amdgcn_mfma_f32_16x16x32_bf16(pa1, vf1, o_acc[dt], 0, 0, 0);
        }
        __syncthreads();
    }

    #pragma unroll
    for (int r = 0; r < 4; r++) {
        const float inv = uniformq ? (1.0f / 1024.0f) : (1.0f / l_r[r]);
        size_t row_g = (size_t)(b*S_ + q0 + wv*16 + quad*4 + r);
        #pragma unroll
        for (int dt = 0; dt < 5; dt++)
            o[row_g*E_ + h*D_ + dt*16 + l15] = f2b(o_acc[dt][r] * inv);
    }
}

extern "C" void kernel_launch(void* const* d_in, const int* in_sizes, int n_in,
                              void* d_out, int out_size, void* d_ws, size_t ws_size,
                              hipStream_t stream)
{
    const float* x    = (const float*)d_in[0];
    const int*   cu   = (const int*)  d_in[1];
    const float* cosp = (const float*)d_in[2];
    const float* sinp = (const float*)d_in[3];
    const float* wq   = (const float*)d_in[4];
    const float* bq   = (const float*)d_in[5];
    const float* wk   = (const float*)d_in[6];
    const float* bk   = (const float*)d_in[7];
    const float* wv   = (const float*)d_in[8];
    const float* bv   = (const float*)d_in[9];
    const float* wo   = (const float*)d_in[10];
    const float* bo   = (const float*)d_in[11];
    float* out = (float*)d_out;

    bf16* q   = (bf16*)d_ws;
    bf16* kk  = q   + (size_t)M_ * E_;
    bf16* vt  = kk  + (size_t)M_ * E_;   // transposed V: [B][H][D][S]
    bf16* ao  = vt  + (size_t)M_ * E_;
    bf16* xb  = ao  + (size_t)M_ * E_;
    bf16* wqb = xb  + (size_t)M_ * E_;
    bf16* wkb = wqb + (size_t)E_ * E_;
    bf16* wvb = wkb + (size_t)E_ * E_;
    bf16* wob = wvb + (size_t)E_ * E_;

    // 0) convert x + 4 weight matrices to bf16
    cvt_kernel<<<dim3(2560, 5), 256, 0, stream>>>(
        x, wq, wk, wv, wo, xb, wqb, wkb, wvb, wob, M_*E_, E_*E_);

    // 1) QKV projection: 256x256 8-phase MFMA GEMM, bias fused; V transposed.
    qkv_gemm_8ph<<<dim3(M_/256, 15), 512, 0, stream>>>(
        xb, wqb, wkb, wvb, bq, bk, bv, q, kk, vt);

    // 1.5) one-shot RoPE on q (pre-scaled) and k, in place
    rope_kernel<<<2560, 256, 0, stream>>>(q, kk, cosp, sinp);

    // 2) MFMA flash attention v10
    attn_mfma<<<512, 512, 0, stream>>>(q, kk, vt, cu, ao);

    // 3) output projection (MFMA 128², BK=64), fp32 out, bias fused
    mfma_gemm_bt<float, false><<<dim3(M_/128, 10), 256, 0, stream>>>(
        ao, wob, wob, wob, bo, bo, bo, out, out, out, E_, E_, 10);
}

// Round 5
// 230.809 us; speedup vs baseline: 1.9988x; 1.1028x over previous
//
#include <hip/hip_runtime.h>
#include <hip/hip_bf16.h>

#define B_ 4
#define S_ 1024
#define E_ 1280
#define H_ 16
#define D_ 80
#define M_ (B_*S_)   // 4096
#define QBLK 128

typedef __hip_bfloat16 bf16;
using bf16x8 = __attribute__((ext_vector_type(8))) short;  // 8 bf16 = 4 VGPRs
using f32x4  = __attribute__((ext_vector_type(4))) float;  // MFMA C/D frag

__device__ __forceinline__ float b2f(bf16 x){ return __bfloat162float(x); }
__device__ __forceinline__ bf16  f2b(float x){ return __float2bfloat16(x); }
__device__ __forceinline__ void  stf(float* p, float v){ *p = v; }
__device__ __forceinline__ void  stf(bf16*  p, float v){ *p = f2b(v); }

__device__ __forceinline__ void gload_lds16(const void* g, void* l) {
    __builtin_amdgcn_global_load_lds(
        (const __attribute__((address_space(1))) unsigned int*)g,
        (__attribute__((address_space(3))) unsigned int*)l, 16, 0, 0);
}

// 8-phase sync helpers (rule #18: sched_barrier(0) after inline waitcnt)
__device__ __forceinline__ void ph_begin() {
    __builtin_amdgcn_s_barrier();
    asm volatile("s_waitcnt lgkmcnt(0)" ::: "memory");
    __builtin_amdgcn_sched_barrier(0);
    __builtin_amdgcn_s_setprio(1);
}
__device__ __forceinline__ void ph_end() {
    __builtin_amdgcn_s_setprio(0);
    __builtin_amdgcn_sched_barrier(0);
    __builtin_amdgcn_s_barrier();
}
__device__ __forceinline__ void ph_end_vm6() {
    __builtin_amdgcn_s_setprio(0);
    __builtin_amdgcn_sched_barrier(0);
    asm volatile("s_waitcnt vmcnt(6)" ::: "memory");
    __builtin_amdgcn_s_barrier();
}
__device__ __forceinline__ void ph_end_vm0() {
    __builtin_amdgcn_s_setprio(0);
    __builtin_amdgcn_sched_barrier(0);
    asm volatile("s_waitcnt vmcnt(0)" ::: "memory");
    __builtin_amdgcn_s_barrier();
}

// fp32 -> bf16 conversion, 8 elems/thread. blockIdx.y selects segment.
__global__ __launch_bounds__(256) void cvt_kernel(
    const float* __restrict__ s0, const float* __restrict__ s1,
    const float* __restrict__ s2, const float* __restrict__ s3,
    const float* __restrict__ s4,
    bf16* __restrict__ d0, bf16* __restrict__ d1, bf16* __restrict__ d2,
    bf16* __restrict__ d3, bf16* __restrict__ d4,
    int n0, int n1)
{
    const float* s; bf16* d; int n;
    switch (blockIdx.y) {
        case 0: s = s0; d = d0; n = n0; break;
        case 1: s = s1; d = d1; n = n1; break;
        case 2: s = s2; d = d2; n = n1; break;
        case 3: s = s3; d = d3; n = n1; break;
        default: s = s4; d = d4; n = n1; break;
    }
    int i = (blockIdx.x * 256 + threadIdx.x) * 8;
    if (i >= n) return;
    float4 a = *(const float4*)(s + i);
    float4 b = *(const float4*)(s + i + 4);
    bf16 t[8];
    t[0]=f2b(a.x); t[1]=f2b(a.y); t[2]=f2b(a.z); t[3]=f2b(a.w);
    t[4]=f2b(b.x); t[5]=f2b(b.y); t[6]=f2b(b.z); t[7]=f2b(b.w);
    *(uint4*)(d + i) = *(const uint4*)t;
}

// ============================================================================
// QKV projection: 256x256 8-phase MFMA GEMM (T2+T3+T4+T5). Unchanged from r4.
// ============================================================================
__global__ __launch_bounds__(512, 2) void qkv_gemm_8ph(
    const bf16* __restrict__ A,
    const bf16* __restrict__ W0, const bf16* __restrict__ W1, const bf16* __restrict__ W2,
    const float* __restrict__ b0, const float* __restrict__ b1, const float* __restrict__ b2,
    bf16* __restrict__ Cq, bf16* __restrict__ Ck, bf16* __restrict__ Cv)
{
    constexpr int K = 1280;
    constexpr int NITER = K / 128;   // 10 iterations, 2 K-tiles each

    __shared__ __align__(16) bf16 Asm[2][2][128*64];   // [buf][half][row*64+col]
    __shared__ __align__(16) bf16 Bsm[2][2][128*64];

    const int bm  = blockIdx.x * 256;
    const int ny  = blockIdx.y;            // 0..14
    const int mat = ny / 5;
    const int bn  = (ny % 5) * 256;        // col base within matrix
    const bf16*  W    = (mat == 0) ? W0 : (mat == 1) ? W1 : W2;
    const float* bias = (mat == 0) ? b0 : (mat == 1) ? b1 : b2;

    const int tid  = threadIdx.x;
    const int lane = tid & 63, wv = tid >> 6;
    const int wm = wv >> 2, wn = wv & 3;        // wave tile: rows wm*128, cols wn*64
    const int quad = lane >> 4, l15 = lane & 15;

    auto stageA = [&](int j_, int half) {
        #pragma unroll
        for (int i = 0; i < 2; i++) {
            const int c   = tid + i*512;
            const int row = c >> 3;
            const int g   = (c & 7) ^ (row & 7);
            gload_lds16(A + (size_t)(bm + half*128 + row) * K + j_*64 + g*8,
                        &Asm[j_ & 1][half][(wv*64 + i*512) * 8]);
        }
    };
    auto stageB = [&](int j_, int half) {
        #pragma unroll
        for (int i = 0; i < 2; i++) {
            const int c   = tid + i*512;
            const int row = c >> 3;
            const int g   = (c & 7) ^ (row & 7);
            gload_lds16(W + (size_t)(bn + half*128 + row) * K + j_*64 + g*8,
                        &Bsm[j_ & 1][half][(wv*64 + i*512) * 8]);
        }
    };
    auto lda = [&](int bf, int mt, int ks) -> bf16x8 {
        const int r = mt*16 + l15;
        return *(const bf16x8*)&Asm[bf][wm][r*64 + (((quad + ks*4) ^ (r & 7)) << 3)];
    };
    auto ldb = [&](int bf, int nt, int ks) -> bf16x8 {
        const int r = (wn & 1)*64 + nt*16 + l15;
        return *(const bf16x8*)&Bsm[bf][wn >> 1][r*64 + (((quad + ks*4) ^ (r & 7)) << 3)];
    };

    f32x4 acc[8][4] = {};
    bf16x8 a[4][2], bA[2][2], bB[2][2];

#define MFMA_Q(MT0, NT0, BB_) do { \
    _Pragma("unroll") for (int mt_ = 0; mt_ < 4; mt_++) \
    _Pragma("unroll") for (int nt_ = 0; nt_ < 2; nt_++) \
    _Pragma("unroll") for (int ks_ = 0; ks_ < 2; ks_++) \
        acc[(MT0)+mt_][(NT0)+nt_] = __builtin_amdgcn_mfma_f32_16x16x32_bf16( \
            a[mt_][ks_], BB_[nt_][ks_], acc[(MT0)+mt_][(NT0)+nt_], 0, 0, 0); \
} while (0)

    stageA(0, 0); stageA(0, 1); stageB(0, 0); stageB(0, 1);
    stageA(1, 0); stageA(1, 1); stageB(1, 0); stageB(1, 1);
    __syncthreads();

    for (int t = 0; t < NITER; t++) {
        const int  j  = 2*t;
        const bool pf = (t + 1 < NITER);

        #pragma unroll
        for (int mt = 0; mt < 4; mt++) { a[mt][0] = lda(0, mt, 0); a[mt][1] = lda(0, mt, 1); }
        #pragma unroll
        for (int nt = 0; nt < 2; nt++) { bA[nt][0] = ldb(0, nt, 0); bA[nt][1] = ldb(0, nt, 1); }
        stageA(j+1, 1);
        ph_begin(); MFMA_Q(0, 0, bA); ph_end();

        #pragma unroll
        for (int nt = 0; nt < 2; nt++) { bB[nt][0] = ldb(0, 2+nt, 0); bB[nt][1] = ldb(0, 2+nt, 1); }
        ph_begin(); MFMA_Q(0, 2, bB); ph_end();

        #pragma unroll
        for (int mt = 0; mt < 4; mt++) { a[mt][0] = lda(0, 4+mt, 0); a[mt][1] = lda(0, 4+mt, 1); }
        if (pf) stageB(j+2, 0);
        ph_begin(); MFMA_Q(4, 0, bA); ph_end();

        if (pf) { stageB(j+2, 1); stageA(j+2, 0); }
        ph_begin(); MFMA_Q(4, 2, bB);
        if (pf) ph_end_vm6(); else ph_end_vm0();

        #pragma unroll
        for (int mt = 0; mt < 4; mt++) { a[mt][0] = lda(1, mt, 0); a[mt][1] = lda(1, mt, 1); }
        #pragma unroll
        for (int nt = 0; nt < 2; nt++) { bA[nt][0] = ldb(1, nt, 0); bA[nt][1] = ldb(1, nt, 1); }
        if (pf) stageA(j+2, 1);
        ph_begin(); MFMA_Q(0, 0, bA); ph_end();

        #pragma unroll
        for (int nt = 0; nt < 2; nt++) { bB[nt][0] = ldb(1, 2+nt, 0); bB[nt][1] = ldb(1, 2+nt, 1); }
        ph_begin(); MFMA_Q(0, 2, bB); ph_end();

        #pragma unroll
        for (int mt = 0; mt < 4; mt++) { a[mt][0] = lda(1, 4+mt, 0); a[mt][1] = lda(1, 4+mt, 1); }
        if (pf) stageB(j+3, 0);
        ph_begin(); MFMA_Q(4, 0, bA); ph_end();

        if (pf) { stageB(j+3, 1); stageA(j+3, 0); }
        ph_begin(); MFMA_Q(4, 2, bB); ph_end_vm6();
    }
#undef MFMA_Q

    if (mat < 2) {
        bf16* C = (mat == 0) ? Cq : Ck;
        #pragma unroll
        for (int nt = 0; nt < 4; nt++) {
            const int ncol = bn + wn*64 + nt*16 + l15;
            const float bv = bias[ncol];
            #pragma unroll
            for (int mt = 0; mt < 8; mt++) {
                const int m0 = bm + wm*128 + mt*16 + quad*4;
                #pragma unroll
                for (int r = 0; r < 4; r++)
                    C[(size_t)(m0 + r) * E_ + ncol] = f2b(acc[mt][nt][r] + bv);
            }
        }
    } else {
        #pragma unroll
        for (int nt = 0; nt < 4; nt++) {
            const int ncol = bn + wn*64 + nt*16 + l15;
            const float bv = bias[ncol];
            const int hh = ncol / 80, dd = ncol % 80;
            #pragma unroll
            for (int mt = 0; mt < 8; mt++) {
                const int m0  = bm + wm*128 + mt*16 + quad*4;
                const int btok = m0 >> 10;
                const int key  = m0 & 1023;
                union { bf16 h[4]; uint2 u; } t4;
                #pragma unroll
                for (int r = 0; r < 4; r++) t4.h[r] = f2b(acc[mt][nt][r] + bv);
                *(uint2*)&Cv[((size_t)(btok*H_ + hh)*D_ + dd)*S_ + key] = t4.u;
            }
        }
    }
}

// m97-style MFMA GEMM, BK=64. Used for the output projection only.
template<typename TC, bool VT_OUT>
__global__ __launch_bounds__(256) void mfma_gemm_bt(
    const bf16* __restrict__ A,
    const bf16* __restrict__ W0, const bf16* __restrict__ W1, const bf16* __restrict__ W2,
    const float* __restrict__ b0, const float* __restrict__ b1, const float* __restrict__ b2,
    TC* __restrict__ C0, TC* __restrict__ C1, TC* __restrict__ C2,
    int K, int N, int ntiles)
{
    const int mat = blockIdx.y / ntiles;
    const int bn  = (blockIdx.y % ntiles) * 128;
    const int bm  = blockIdx.x * 128;
    const bf16* W; const float* bias; TC* C;
    if (mat == 0)      { W = W0; bias = b0; C = C0; }
    else if (mat == 1) { W = W1; bias = b1; C = C1; }
    else               { W = W2; bias = b2; C = C2; }

    __shared__ bf16 As[2][128][32];
    __shared__ bf16 Ws[2][128][32];

    const int tid  = threadIdx.x;
    const int lane = tid & 63;
    const int wv   = tid >> 6;
    const int wm   = (wv & 1) * 64;
    const int wn   = (wv >> 1) * 64;
    const int srow = wv * 16 + (lane >> 2);
    const int scol = (lane & 3) * 8;

    f32x4 acc[4][4] = {};

    for (int k0 = 0; k0 < K; k0 += 64) {
        __syncthreads();
        #pragma unroll
        for (int p = 0; p < 2; p++) {
            const int kc = k0 + p*32 + scol;
            gload_lds16(A + (size_t)(bm + srow)      * K + kc, &As[p][wv*16][0]);
            gload_lds16(A + (size_t)(bm + 64 + srow) * K + kc, &As[p][64 + wv*16][0]);
            gload_lds16(W + (size_t)(bn + srow)      * K + kc, &Ws[p][wv*16][0]);
            gload_lds16(W + (size_t)(bn + 64 + srow) * K + kc, &Ws[p][64 + wv*16][0]);
        }
        __syncthreads();

        const int fr = lane & 15;
        const int kq = (lane >> 4) * 8;
        #pragma unroll
        for (int p = 0; p < 2; p++) {
            bf16x8 af[4], wf[4];
            #pragma unroll
            for (int t = 0; t < 4; t++) {
                af[t] = *(const bf16x8*)&As[p][wm + t*16 + fr][kq];
                wf[t] = *(const bf16x8*)&Ws[p][wn + t*16 + fr][kq];
            }
            #pragma unroll
            for (int mt = 0; mt < 4; mt++)
                #pragma unroll
                for (int nt = 0; nt < 4; nt++)
                    acc[mt][nt] = __builtin_amdgcn_mfma_f32_16x16x32_bf16(
                        af[mt], wf[nt], acc[mt][nt], 0, 0, 0);
        }
    }

    const int col_l = lane & 15;
    const int row_l = (lane >> 4) * 4;

    if (VT_OUT && mat == 2) {
        const int btok = bm >> 10;
        const int keyb = (bm & 1023) + wm + row_l;
        #pragma unroll
        for (int nt = 0; nt < 4; nt++) {
            const int n = bn + wn + nt*16 + col_l;
            const float bv = bias[n];
            const int hh = n / 80, dd = n % 80;
            bf16* vbase = (bf16*)C + ((size_t)(btok*H_ + hh)*D_ + dd)*S_ + keyb;
            #pragma unroll
            for (int mt = 0; mt < 4; mt++) {
                union { bf16 h[4]; uint2 u; } t4;
                #pragma unroll
                for (int r = 0; r < 4; r++) t4.h[r] = f2b(acc[mt][nt][r] + bv);
                *(uint2*)&vbase[mt*16] = t4.u;
            }
        }
    } else {
        #pragma unroll
        for (int nt = 0; nt < 4; nt++) {
            const int n = bn + wn + nt*16 + col_l;
            const float bv = bias[n];
            #pragma unroll
            for (int mt = 0; mt < 4; mt++) {
                #pragma unroll
                for (int r = 0; r < 4; r++) {
                    const int m = bm + wm + mt*16 + row_l + r;
                    stf(&C[(size_t)m * N + n], acc[mt][nt][r] + bv);
                }
            }
        }
    }
}

// rope helper
__device__ __forceinline__ void rope8(const bf16* lo, const bf16* hi,
                                      const float* cp, const float* sp,
                                      float mul, uint4* out_lo, uint4* out_hi)
{
    union { uint4 u; bf16 h[8]; } li, hi_, lo_o, hi_o;
    li.u  = *(const uint4*)lo;
    hi_.u = *(const uint4*)hi;
    #pragma unroll
    for (int u = 0; u < 8; u++) {
        float x1 = b2f(li.h[u]), x2 = b2f(hi_.h[u]);
        float c = cp[u], s = sp[u];
        lo_o.h[u] = f2b((x1*c - x2*s) * mul);
        hi_o.h[u] = f2b((x2*c + x1*s) * mul);
    }
    *out_lo = lo_o.u;
    *out_hi = hi_o.u;
}

// One-shot in-place RoPE over q and k. Q additionally pre-scaled by 1/sqrt(80).
__global__ __launch_bounds__(256) void rope_kernel(
    bf16* __restrict__ qp, bf16* __restrict__ kp,
    const float* __restrict__ cosp, const float* __restrict__ sinp)
{
    int idx = blockIdx.x * 256 + threadIdx.x;
    const int NT = M_ * H_ * 5;   // 327680
    bf16* base; float mul;
    if (idx < NT) { base = qp; mul = 0.11180339887498949f; }
    else         { base = kp; mul = 1.0f; idx -= NT; }
    const int row = idx / 80;
    const int rem = idx - row * 80;
    const int h   = rem / 5;
    const int pc  = rem - h * 5;
    const int s   = row & (S_ - 1);
    bf16* p = base + (size_t)row * E_ + h * D_ + pc * 8;
    const float* cp = cosp + s * D_ + pc * 8;
    const float* sp = sinp + s * D_ + pc * 8;
    uint4 olo, ohi;
    rope8(p, p + 40, cp, sp, mul, &olo, &ohi);
    *(uint4*)p        = olo;
    *(uint4*)(p + 40) = ohi;
}

// ============================================================================
// MFMA flash attention v11 — swapped-operand softmax (reduction lane-local).
// r4 diagnosis: ~72 DS-pipe ops per wave-tile (24 b128 reads + 16 scalar PT
// writes + 32 shuffle ops) + a 4-stage shuffle dependency chain; DS pipe ~55%+
// occupied -> the limiter. v11 computes QK^T as mfma(K, Q): C[key][query],
// each lane owns ONE query (l15) and 16 keys:
//  - softmax: 15 in-reg fmax + 2 shuffles (xor16/32); m/l scalar per lane.
//  - P is written [query][key]: 4 ds_write_b64 + 2 ds_read_b128 (granule-XOR
//    swizzled, conflict-free) vs 16 scalar writes.
//  - PV = mfma(Vfrag, Pfrag) -> O[d][q]; epilogue packs 5x8B stores.
//  - uniform path: Pfrag = splat(1.0) in registers, zero LDS.
// K/V staging (gload_lds + swizzle + dbuf pipeline), XCD mapping unchanged.
// LDS: 2*10240*2 + 8*2048 = 57344 B -> 2 blocks/CU.
// ============================================================================
__global__ __launch_bounds__(512, 4) void attn_mfma(
    const bf16* __restrict__ q, const bf16* __restrict__ k, const bf16* __restrict__ vt,
    const int* __restrict__ cu, bf16* __restrict__ o)
{
    __shared__ __align__(16) bf16 Ks[2][64*80];    // 2 x 10240 B, swizzled
    __shared__ __align__(16) bf16 VTs[2][80*64];   // 2 x 10240 B, swizzled
    __shared__ __align__(16) bf16 PTq[8][16*64];   // per-wave P [query][key], swizzled

    const int n  = blockIdx.x;                 // 512 blocks
    const int g  = ((n >> 6) << 3) | (n & 7);  // (b,h): XCD = n&7 = h&7
    const int qs = (n >> 3) & 7;               // q-supertile 0..7 (128 rows)
    const int b  = g >> 4;
    const int h  = g & 15;

    const int tid  = threadIdx.x;
    const int lane = tid & 63, wv = tid >> 6;  // wv 0..7
    const int quad = lane >> 4, l15 = lane & 15;
    const int q0   = qs * QBLK;
    const int len  = cu[b + 1] - cu[b];

    const bool uniformq = (q0 >= len);
    const bool clean    = ((len & (QBLK - 1)) == 0);
    const int  ktiles   = uniformq ? 16 : (clean ? (len >> 6) : 16);
    const bool domask   = !uniformq && !clean;

    bf16* PT = &PTq[wv][0];

    // Q fragments straight to registers (pre-roped, pre-scaled); B-operand.
    bf16x8 qf[3] = {};
    if (!uniformq) {
        const bf16* qrow = q + (size_t)(b*S_ + q0 + wv*16 + l15)*E_ + h*D_ + quad*8;
        qf[0] = *(const bf16x8*)(qrow);
        qf[1] = *(const bf16x8*)(qrow + 32);
        if (quad < 2) qf[2] = *(const bf16x8*)(qrow + 64);
    }

    float m_s = -1e30f, l_s = 0.f;   // per-lane scalars (query = l15)
    f32x4 o_acc[5] = {};

    // P-frag of all-ones for the uniform path
    bf16x8 pone;
    {
        const short one_s = (short)0x3F80;   // bf16 1.0
        #pragma unroll
        for (int i = 0; i < 8; i++) pone[i] = one_s;
    }

    // per-lane swizzled read slots (K and V staging layouts unchanged)
    const int u_  = l15 >> 2;
    const int s0r = quad ^ u_;            // K granule ks=0; ks=1: +32; ks=2: &1
    const int sv0 = quad ^ (l15 & 7);     // V granule ks=0; ks=1: ^4

    auto stage = [&](int kt, int bf) {
        #pragma unroll
        for (int i = 0; i < 3; i++) {
            int c = tid + i * 512;
            if (c < 640) {
                if (!uniformq) {
                    int row = c / 10, s5 = c - row * 10;
                    int uu = (row >> 2) & 3;
                    int sg = (s5 < 8) ? (s5 ^ uu) : (8 + ((s5 ^ uu) & 1));
                    gload_lds16(k + (size_t)(b*S_ + kt*64 + row)*E_ + h*D_ + sg*8,
                                &Ks[bf][c*8]);
                }
            } else if (c < 1280) {
                int c2 = c - 640;
                int row = c2 >> 3, s5 = c2 & 7;
                int sg = s5 ^ (row & 7);
                gload_lds16(vt + ((size_t)(b*H_ + h)*D_ + row)*S_ + kt*64 + sg*8,
                            &VTs[bf][c2*8]);
            }
        }
    };

    stage(0, 0);
    __syncthreads();   // buf0 ready

    const bool q_full = (q0 + 64) <= len;   // masked-fallback helper

    for (int kt = 0; kt < ktiles; kt++) {
        const int cur = kt & 1;
        if (kt + 1 < ktiles) stage(kt + 1, cur ^ 1);   // loads fly during compute

        bf16x8 pf0 = pone, pf1 = pone;
        if (!uniformq) {
            // ---- QK^T swapped: A=K, B=Q -> C[key=quad*4+r (+nt*16)][query=l15]
            f32x4 s4[4];
            #pragma unroll
            for (int nt = 0; nt < 4; nt++) {
                const bf16* kr = &Ks[cur][(nt*16 + l15) * 80];
                bf16x8 kf0 = *(const bf16x8*)(kr + s0r*8);
                bf16x8 kf1 = *(const bf16x8*)(kr + 32 + s0r*8);
                bf16x8 kf2 = {};
                if (quad < 2) kf2 = *(const bf16x8*)(kr + 64 + (s0r & 1)*8);
                f32x4 a0 = {};
                a0 = __builtin_amdgcn_mfma_f32_16x16x32_bf16(kf0, qf[0], a0, 0, 0, 0);
                a0 = __builtin_amdgcn_mfma_f32_16x16x32_bf16(kf1, qf[1], a0, 0, 0, 0);
                a0 = __builtin_amdgcn_mfma_f32_16x16x32_bf16(kf2, qf[2], a0, 0, 0, 0);
                s4[nt] = a0;
            }

            // ---- masking (lane owns query l15; keys nt*16+quad*4+r)
            float sv[4][4];
            if (!domask || (q_full && (kt*64 + 64) <= len)) {
                #pragma unroll
                for (int nt = 0; nt < 4; nt++)
                    #pragma unroll
                    for (int r = 0; r < 4; r++)
                        sv[nt][r] = s4[nt][r];
            } else {
                const bool vq = (q0 + wv*16 + l15) < len;
                #pragma unroll
                for (int nt = 0; nt < 4; nt++)
                    #pragma unroll
                    for (int r = 0; r < 4; r++) {
                        const bool vk = (kt*64 + nt*16 + quad*4 + r) < len;
                        sv[nt][r] = (vq && vk) ? s4[nt][r] : -1e9f;
                    }
            }

            // ---- online softmax: in-register max + 2 shuffles
            float rm[4];
            #pragma unroll
            for (int nt = 0; nt < 4; nt++)
                rm[nt] = fmaxf(fmaxf(sv[nt][0], sv[nt][1]), fmaxf(sv[nt][2], sv[nt][3]));
            float sloc = fmaxf(fmaxf(rm[0], rm[1]), fmaxf(rm[2], rm[3]));
            sloc = fmaxf(sloc, __shfl_xor(sloc, 16, 64));
            sloc = fmaxf(sloc, __shfl_xor(sloc, 32, 64));
            const float mnew  = fmaxf(m_s, sloc);
            const float alpha = __expf(m_s - mnew);
            float p[4][4], lsum = 0.f;
            #pragma unroll
            for (int nt = 0; nt < 4; nt++)
                #pragma unroll
                for (int r = 0; r < 4; r++) {
                    p[nt][r] = __expf(sv[nt][r] - mnew);
                    lsum += p[nt][r];
                }
            lsum += __shfl_xor(lsum, 16, 64);
            lsum += __shfl_xor(lsum, 32, 64);
            l_s = l_s * alpha + lsum;
            m_s = mnew;
            #pragma unroll
            for (int dt = 0; dt < 5; dt++)
                #pragma unroll
                for (int r = 0; r < 4; r++)
                    o_acc[dt][r] *= alpha;

            // ---- P -> PTq[query][key] (granule-swizzled), 4 x b64 writes
            #pragma unroll
            for (int nt = 0; nt < 4; nt++) {
                union { bf16 hh[4]; uint2 u; } w;
                #pragma unroll
                for (int r = 0; r < 4; r++) w.hh[r] = f2b(p[nt][r]);
                const int gw = (2*nt + (quad >> 1)) ^ (l15 & 7);
                *(uint2*)&PT[l15*64 + gw*8 + (quad & 1)*4] = w.u;
            }
            // ---- P-frags (same-wave RAW via lgkmcnt), 2 x b128 reads
            pf0 = *(const bf16x8*)&PT[l15*64 + ((quad    ) ^ (l15 & 7))*8];
            pf1 = *(const bf16x8*)&PT[l15*64 + ((quad + 4) ^ (l15 & 7))*8];
        }

        // ---- PV: A=Vfrag, B=Pfrag -> O[d=quad*4+r (+dt*16)][query=l15]
        #pragma unroll
        for (int dt = 0; dt < 5; dt++) {
            const bf16* vr = &VTs[cur][(dt*16 + l15) * 64];
            bf16x8 vf0 = *(const bf16x8*)(vr + sv0*8);
            bf16x8 vf1 = *(const bf16x8*)(vr + (sv0 ^ 4)*8);
            o_acc[dt] = __builtin_amdgcn_mfma_f32_16x16x32_bf16(vf0, pf0, o_acc[dt], 0, 0, 0);
            o_acc[dt] = __builtin_amdgcn_mfma_f32_16x16x32_bf16(vf1, pf1, o_acc[dt], 0, 0, 0);
        }
        __syncthreads();   // reads of buf[cur] done; buf[cur^1] loads drained
    }

    // ---- epilogue: lane = query l15; d = dt*16 + quad*4 + r (4 consecutive)
    const float inv = uniformq ? (1.0f / 1024.0f) : (1.0f / l_s);
    const size_t row_g = (size_t)(b*S_ + q0 + wv*16 + l15);
    #pragma unroll
    for (int dt = 0; dt < 5; dt++) {
        union { bf16 hh[4]; uint2 u; } t4;
        #pragma unroll
        for (int r = 0; r < 4; r++) t4.hh[r] = f2b(o_acc[dt][r] * inv);
        *(uint2*)&o[row_g*E_ + h*D_ + dt*16 + quad*4] = t4.u;
    }
}

extern "C" void kernel_launch(void* const* d_in, const int* in_sizes, int n_in,
                              void* d_out, int out_size, void* d_ws, size_t ws_size,
                              hipStream_t stream)
{
    const float* x    = (const float*)d_in[0];
    const int*   cu   = (const int*)  d_in[1];
    const float* cosp = (const float*)d_in[2];
    const float* sinp = (const float*)d_in[3];
    const float* wq   = (const float*)d_in[4];
    const float* bq   = (const float*)d_in[5];
    const float* wk   = (const float*)d_in[6];
    const float* bk   = (const float*)d_in[7];
    const float* wv   = (const float*)d_in[8];
    const float* bv   = (const float*)d_in[9];
    const float* wo   = (const float*)d_in[10];
    const float* bo   = (const float*)d_in[11];
    float* out = (float*)d_out;

    bf16* q   = (bf16*)d_ws;
    bf16* kk  = q   + (size_t)M_ * E_;
    bf16* vt  = kk  + (size_t)M_ * E_;   // transposed V: [B][H][D][S]
    bf16* ao  = vt  + (size_t)M_ * E_;
    bf16* xb  = ao  + (size_t)M_ * E_;
    bf16* wqb = xb  + (size_t)M_ * E_;
    bf16* wkb = wqb + (size_t)E_ * E_;
    bf16* wvb = wkb + (size_t)E_ * E_;
    bf16* wob = wvb + (size_t)E_ * E_;

    // 0) convert x + 4 weight matrices to bf16
    cvt_kernel<<<dim3(2560, 5), 256, 0, stream>>>(
        x, wq, wk, wv, wo, xb, wqb, wkb, wvb, wob, M_*E_, E_*E_);

    // 1) QKV projection: 256x256 8-phase MFMA GEMM, bias fused; V transposed.
    qkv_gemm_8ph<<<dim3(M_/256, 15), 512, 0, stream>>>(
        xb, wqb, wkb, wvb, bq, bk, bv, q, kk, vt);

    // 1.5) one-shot RoPE on q (pre-scaled) and k, in place
    rope_kernel<<<2560, 256, 0, stream>>>(q, kk, cosp, sinp);

    // 2) MFMA flash attention v11 (swapped-operand softmax)
    attn_mfma<<<512, 512, 0, stream>>>(q, kk, vt, cu, ao);

    // 3) output projection (MFMA 128², BK=64), fp32 out, bias fused
    mfma_gemm_bt<float, false><<<dim3(M_/128, 10), 256, 0, stream>>>(
        ao, wob, wob, wob, bo, bo, bo, out, out, out, E_, E_, 10);
}